// Round 1
// baseline (630.303 us; speedup 1.0000x reference)
//
#include <hip/hip_runtime.h>

#define NN 50000
#define NE 800000
#define F  128
#define FO 32

// ---------------- degree histogram ----------------
__global__ void k_deg(const int* __restrict__ dst, int* __restrict__ degi) {
    int e = blockIdx.x * 256 + threadIdx.x;
    if (e < NE) atomicAdd(&degi[dst[e]], 1);
}

// ---------------- exclusive scan (single block, shfl-based) ----------------
__global__ __launch_bounds__(1024) void k_scan(const int* __restrict__ degi,
        float* __restrict__ degf, int* __restrict__ offs, int* __restrict__ cursor) {
    __shared__ int wpre[17];
    __shared__ int carry;
    const int tid  = threadIdx.x;
    const int lane = tid & 63;
    const int wv   = tid >> 6;     // 0..15
    if (tid == 0) carry = 0;
    __syncthreads();
    for (int base = 0; base < NN; base += 1024) {
        int i = base + tid;
        int v = (i < NN) ? degi[i] : 0;
        if (i < NN) degf[i] = (float)v;
        int incl = v;
        #pragma unroll
        for (int d = 1; d < 64; d <<= 1) {
            int t = __shfl_up(incl, d, 64);
            if (lane >= d) incl += t;
        }
        if (lane == 63) wpre[wv + 1] = incl;
        __syncthreads();
        if (tid == 0) {
            wpre[0] = carry;
            #pragma unroll
            for (int w = 1; w <= 16; ++w) wpre[w] += wpre[w - 1];
            carry = wpre[16];
        }
        __syncthreads();
        if (i < NN) {
            int excl = wpre[wv] + incl - v;
            offs[i]   = excl;
            cursor[i] = excl;
        }
        __syncthreads();   // protect wpre before next tile
    }
    if (tid == 0) offs[NN] = carry;
}

// ---------------- CSR fill ----------------
__global__ void k_fill(const int* __restrict__ src, const int* __restrict__ dst,
                       int* __restrict__ cursor, int* __restrict__ csr) {
    int e = blockIdx.x * 256 + threadIdx.x;
    if (e < NE) {
        int p = atomicAdd(&cursor[dst[e]], 1);
        csr[p] = src[e];
    }
}

// ---------------- row L2 normalize (one wave per row) ----------------
__global__ __launch_bounds__(256) void k_l2norm(const float* __restrict__ x,
                                                float* __restrict__ h) {
    const int wid  = (int)((blockIdx.x * 256 + threadIdx.x) >> 6);
    const int lane = threadIdx.x & 63;
    if (wid >= NN) return;
    const float2* xr = (const float2*)(x + (size_t)wid * F);
    float2 v = xr[lane];
    float ss = v.x * v.x + v.y * v.y;
    #pragma unroll
    for (int d = 1; d < 64; d <<= 1) ss += __shfl_xor(ss, d, 64);
    float inv = 1.0f / fmaxf(sqrtf(ss), 1e-12f);
    ((float2*)(h + (size_t)wid * F))[lane] = make_float2(v.x * inv, v.y * inv);
}

// ---------------- fp32 GEMM: out[N][NC] = h[N][128] @ W[128][NC] ----------------
// 256 threads, thread tile 4 rows x 8 cols, K chunked by 32, W+h^T staged in LDS.
template<int NC>
__global__ __launch_bounds__(256) void k_gemm(const float* __restrict__ h,
        const float* __restrict__ W, float* __restrict__ out) {
    constexpr int COLG = NC / 8;        // 16 (NC=128) or 4 (NC=32)
    constexpr int ROWG = 256 / COLG;    // 16 or 64
    constexpr int BR   = ROWG * 4;      // 64 or 256
    constexpr int KC   = 32;
    __shared__ float Ws[KC * NC];       // 16KB or 4KB
    __shared__ float HsT[KC][BR + 4];   // padded stride (16B aligned, conflict-spread)
    const int tid  = threadIdx.x;
    const int c0   = (tid % COLG) * 8;
    const int r0   = (tid / COLG) * 4;
    const int brow = blockIdx.x * BR;
    float acc[4][8];
    #pragma unroll
    for (int r = 0; r < 4; ++r)
        #pragma unroll
        for (int c = 0; c < 8; ++c) acc[r][c] = 0.f;

    for (int kc = 0; kc < F; kc += KC) {
        // stage W chunk (contiguous KC*NC floats)
        for (int idx = tid * 4; idx < KC * NC; idx += 1024)
            *(float4*)(Ws + idx) = *(const float4*)(W + kc * NC + idx);
        // stage h tile transposed: HsT[k][r] = h[brow+r][kc+k]
        #pragma unroll
        for (int pass = 0; pass < BR / 32; ++pass) {
            int r  = pass * 32 + tid / 8;
            int k4 = (tid % 8) * 4;
            int gr = brow + r; if (gr > NN - 1) gr = NN - 1;
            float4 hv = *(const float4*)(h + (size_t)gr * F + kc + k4);
            HsT[k4 + 0][r] = hv.x;
            HsT[k4 + 1][r] = hv.y;
            HsT[k4 + 2][r] = hv.z;
            HsT[k4 + 3][r] = hv.w;
        }
        __syncthreads();
        #pragma unroll
        for (int k = 0; k < KC; ++k) {
            float4 hv = *(const float4*)(&HsT[k][r0]);
            float4 wa = *(const float4*)(Ws + k * NC + c0);
            float4 wb = *(const float4*)(Ws + k * NC + c0 + 4);
            float hr[4] = {hv.x, hv.y, hv.z, hv.w};
            float wc[8] = {wa.x, wa.y, wa.z, wa.w, wb.x, wb.y, wb.z, wb.w};
            #pragma unroll
            for (int r = 0; r < 4; ++r)
                #pragma unroll
                for (int c = 0; c < 8; ++c)
                    acc[r][c] += hr[r] * wc[c];
        }
        __syncthreads();
    }
    #pragma unroll
    for (int r = 0; r < 4; ++r) {
        int gr = brow + r0 + r;
        if (gr < NN) {
            *(float4*)(out + (size_t)gr * NC + c0) =
                make_float4(acc[r][0], acc[r][1], acc[r][2], acc[r][3]);
            *(float4*)(out + (size_t)gr * NC + c0 + 4) =
                make_float4(acc[r][4], acc[r][5], acc[r][6], acc[r][7]);
        }
    }
}

// ---------------- aggregation + epilogue, d=128 (one wave per node) ----------------
// MODE 0: mean  -> relu(s[v] + agg/max(deg,1) + b)
// MODE 1: gcn   -> relu((agg + g[v])/(deg+1) + b)
template<int MODE>
__global__ __launch_bounds__(256) void k_agg128(const float* __restrict__ g,
        const float* __restrict__ s, const int* __restrict__ offs,
        const int* __restrict__ csr, const float* __restrict__ degf,
        const float* __restrict__ b, float* __restrict__ out) {
    const int wid  = (int)((blockIdx.x * 256 + threadIdx.x) >> 6);
    const int lane = threadIdx.x & 63;
    if (wid >= NN) return;
    const int beg = offs[wid], end = offs[wid + 1];
    const float2* g2 = (const float2*)g;
    float ax = 0.f, ay = 0.f;
    int e = beg;
    for (; e + 1 < end; e += 2) {           // 2-deep to get 2 loads in flight
        int u0 = csr[e], u1 = csr[e + 1];
        float2 v0 = g2[(size_t)u0 * 64 + lane];
        float2 v1 = g2[(size_t)u1 * 64 + lane];
        ax += v0.x + v1.x; ay += v0.y + v1.y;
    }
    if (e < end) {
        float2 v = g2[(size_t)csr[e] * 64 + lane];
        ax += v.x; ay += v.y;
    }
    const float dg = degf[wid];
    float2 bb = ((const float2*)b)[lane];
    float ox, oy;
    if (MODE == 0) {
        float inv = 1.f / fmaxf(dg, 1.f);
        float2 sv = ((const float2*)s)[(size_t)wid * 64 + lane];
        ox = fmaxf(sv.x + ax * inv + bb.x, 0.f);
        oy = fmaxf(sv.y + ay * inv + bb.y, 0.f);
    } else {
        float inv = 1.f / (dg + 1.f);
        float2 gv = g2[(size_t)wid * 64 + lane];
        ox = fmaxf((ax + gv.x) * inv + bb.x, 0.f);
        oy = fmaxf((ay + gv.y) * inv + bb.y, 0.f);
    }
    ((float2*)out)[(size_t)wid * 64 + lane] = make_float2(ox, oy);
}

// ---------------- aggregation + epilogue, d=32 (mean, no relu, final layer) -------
__global__ __launch_bounds__(256) void k_agg32(const float* __restrict__ g,
        const float* __restrict__ s, const int* __restrict__ offs,
        const int* __restrict__ csr, const float* __restrict__ degf,
        const float* __restrict__ b, float* __restrict__ out) {
    const int wid  = (int)((blockIdx.x * 256 + threadIdx.x) >> 6);
    const int lane = threadIdx.x & 63;
    if (wid >= NN || lane >= 32) return;
    const int beg = offs[wid], end = offs[wid + 1];
    float a = 0.f;
    int e = beg;
    for (; e + 1 < end; e += 2) {
        int u0 = csr[e], u1 = csr[e + 1];
        a += g[(size_t)u0 * 32 + lane] + g[(size_t)u1 * 32 + lane];
    }
    if (e < end) a += g[(size_t)csr[e] * 32 + lane];
    const float inv = 1.f / fmaxf(degf[wid], 1.f);
    out[(size_t)wid * 32 + lane] = s[(size_t)wid * 32 + lane] + a * inv + b[lane];
}

extern "C" void kernel_launch(void* const* d_in, const int* in_sizes, int n_in,
                              void* d_out, int out_size, void* d_ws, size_t ws_size,
                              hipStream_t stream) {
    const float* x       = (const float*)d_in[0];
    const int*   src     = (const int*)  d_in[1];
    const int*   dst     = (const int*)  d_in[2];
    const float* Wself0  = (const float*)d_in[3];
    const float* Wneigh0 = (const float*)d_in[4];
    const float* b0      = (const float*)d_in[5];
    const float* Wneigh1 = (const float*)d_in[6];
    const float* b1      = (const float*)d_in[7];
    const float* Wneigh2 = (const float*)d_in[8];
    const float* b2      = (const float*)d_in[9];
    const float* Wself3  = (const float*)d_in[10];
    const float* Wneigh3 = (const float*)d_in[11];
    const float* b3      = (const float*)d_in[12];
    float* out = (float*)d_out;

    char* ws = (char*)d_ws;
    size_t off = 0;
    auto alloc = [&](size_t bytes) -> void* {
        void* p = ws + off;
        off += (bytes + 255) & ~(size_t)255;
        return p;
    };
    int*   degi   = (int*)  alloc((size_t)NN * 4);
    float* degf   = (float*)alloc((size_t)NN * 4);
    int*   offs   = (int*)  alloc((size_t)(NN + 1) * 4);
    int*   cursor = (int*)  alloc((size_t)(NN + 1) * 4);
    int*   csr    = (int*)  alloc((size_t)NE * 4);
    float* bufh   = (float*)alloc((size_t)NN * F * 4);
    float* bufg   = (float*)alloc((size_t)NN * F * 4);
    float* bufs   = (float*)alloc((size_t)NN * F * 4);

    hipMemsetAsync(degi, 0, (size_t)NN * 4, stream);

    const int egrid = (NE + 255) / 256;
    const int wgrid = (NN + 3) / 4;           // one wave per node
    const int g128  = (NN + 63) / 64;
    const int g32   = (NN + 255) / 256;

    k_deg <<<egrid, 256, 0, stream>>>(dst, degi);
    k_scan<<<1, 1024, 0, stream>>>(degi, degf, offs, cursor);
    k_fill<<<egrid, 256, 0, stream>>>(src, dst, cursor, csr);
    k_l2norm<<<wgrid, 256, 0, stream>>>(x, bufh);

    // layer 0 (mean): transform-then-aggregate (linearity of segment_sum)
    k_gemm<F><<<g128, 256, 0, stream>>>(bufh, Wself0, bufs);
    k_gemm<F><<<g128, 256, 0, stream>>>(bufh, Wneigh0, bufg);
    k_agg128<0><<<wgrid, 256, 0, stream>>>(bufg, bufs, offs, csr, degf, b0, bufh);

    // layer 1 (gcn)
    k_gemm<F><<<g128, 256, 0, stream>>>(bufh, Wneigh1, bufg);
    k_agg128<1><<<wgrid, 256, 0, stream>>>(bufg, nullptr, offs, csr, degf, b1, bufh);

    // layer 2 (gcn)
    k_gemm<F><<<g128, 256, 0, stream>>>(bufh, Wneigh2, bufg);
    k_agg128<1><<<wgrid, 256, 0, stream>>>(bufg, nullptr, offs, csr, degf, b2, bufh);

    // layer 3 (mean, 128->32): aggregate AFTER transform => 4x less gather traffic
    k_gemm<FO><<<g32, 256, 0, stream>>>(bufh, Wself3, bufs);
    k_gemm<FO><<<g32, 256, 0, stream>>>(bufh, Wneigh3, bufg);
    k_agg32<<<wgrid, 256, 0, stream>>>(bufg, bufs, offs, csr, degf, b3, out);
}

// Round 3
// 534.125 us; speedup vs baseline: 1.1801x; 1.1801x over previous
//
#include <hip/hip_runtime.h>

#define NN 50000
#define NE 800000
#define F  128
#define FO 32
#define NB 49   // ceil(NN/1024)

// ---------------- degree histogram ----------------
__global__ void k_deg(const int* __restrict__ dst, int* __restrict__ degi) {
    int e = blockIdx.x * 256 + threadIdx.x;
    if (e < NE) atomicAdd(&degi[dst[e]], 1);
}

// ---------------- parallel scan, stage 1: per-block sums (+degf) ----------------
__global__ __launch_bounds__(1024) void k_bsum(const int* __restrict__ degi,
        float* __restrict__ degf, int* __restrict__ bsum) {
    const int tid  = threadIdx.x;
    const int lane = tid & 63;
    const int wv   = tid >> 6;
    int i = blockIdx.x * 1024 + tid;
    int v = (i < NN) ? degi[i] : 0;
    if (i < NN) degf[i] = (float)v;
    int s = v;
    #pragma unroll
    for (int d = 1; d < 64; d <<= 1) s += __shfl_xor(s, d, 64);
    __shared__ int ws[16];
    if (lane == 0) ws[wv] = s;
    __syncthreads();
    if (tid < 16) {
        int t = ws[tid];
        #pragma unroll
        for (int d = 1; d < 16; d <<= 1) t += __shfl_xor(t, d, 64);
        if (tid == 0) bsum[blockIdx.x] = t;
    }
}

// ---------------- scan stage 2: scan 49 block sums (one wave) ----------------
__global__ void k_bscan(const int* __restrict__ bsum, int* __restrict__ bpre,
                        int* __restrict__ offs) {
    int lane = threadIdx.x;
    int v = (lane < NB) ? bsum[lane] : 0;
    int incl = v;
    #pragma unroll
    for (int d = 1; d < 64; d <<= 1) {
        int t = __shfl_up(incl, d, 64);
        if (lane >= d) incl += t;
    }
    if (lane < NB) bpre[lane] = incl - v;
    if (lane == 63) offs[NN] = incl;
}

// ---------------- scan stage 3: scatter exclusive offsets ----------------
__global__ __launch_bounds__(1024) void k_bscatter(const int* __restrict__ degi,
        const int* __restrict__ bpre, int* __restrict__ offs, int* __restrict__ cursor) {
    const int tid  = threadIdx.x;
    const int lane = tid & 63;
    const int wv   = tid >> 6;
    int i = blockIdx.x * 1024 + tid;
    int v = (i < NN) ? degi[i] : 0;
    int incl = v;
    #pragma unroll
    for (int d = 1; d < 64; d <<= 1) {
        int t = __shfl_up(incl, d, 64);
        if (lane >= d) incl += t;
    }
    __shared__ int wsum[16];
    __shared__ int wpre[16];
    if (lane == 63) wsum[wv] = incl;
    __syncthreads();
    if (tid == 0) {
        int run = 0;
        #pragma unroll
        for (int w = 0; w < 16; ++w) { wpre[w] = run; run += wsum[w]; }
    }
    __syncthreads();
    if (i < NN) {
        int excl = bpre[blockIdx.x] + wpre[wv] + incl - v;
        offs[i]   = excl;
        cursor[i] = excl;
    }
}

// ---------------- CSR fill ----------------
__global__ void k_fill(const int* __restrict__ src, const int* __restrict__ dst,
                       int* __restrict__ cursor, int* __restrict__ csr) {
    int e = blockIdx.x * 256 + threadIdx.x;
    if (e < NE) {
        int p = atomicAdd(&cursor[dst[e]], 1);
        csr[p] = src[e];
    }
}

// ---------------- row L2 normalize (one wave per row) ----------------
__global__ __launch_bounds__(256) void k_l2norm(const float* __restrict__ x,
                                                float* __restrict__ h) {
    const int wid  = (int)((blockIdx.x * 256 + threadIdx.x) >> 6);
    const int lane = threadIdx.x & 63;
    if (wid >= NN) return;
    const float2* xr = (const float2*)(x + (size_t)wid * F);
    float2 v = xr[lane];
    float ss = v.x * v.x + v.y * v.y;
    #pragma unroll
    for (int d = 1; d < 64; d <<= 1) ss += __shfl_xor(ss, d, 64);
    float inv = 1.0f / fmaxf(sqrtf(ss), 1e-12f);
    ((float2*)(h + (size_t)wid * F))[lane] = make_float2(v.x * inv, v.y * inv);
}

// ---------------- fp32 GEMM 128x128: 8x8 thread tile, BR=128, KC=32 -------------
__global__ __launch_bounds__(256) void k_gemm128(const float* __restrict__ h,
        const float* __restrict__ W, float* __restrict__ out) {
    __shared__ float Ws[32][128];
    __shared__ float HsT[32][132];
    const int tid  = threadIdx.x;
    const int c0   = (tid & 15) * 8;
    const int r0   = (tid >> 4) * 8;
    const int brow = blockIdx.x * 128;
    float acc[8][8];
    #pragma unroll
    for (int r = 0; r < 8; ++r)
        #pragma unroll
        for (int c = 0; c < 8; ++c) acc[r][c] = 0.f;

    for (int kc = 0; kc < F; kc += 32) {
        #pragma unroll
        for (int p = 0; p < 4; ++p) {
            int idx = p * 1024 + tid * 4;
            *(float4*)(&Ws[0][0] + idx) = *(const float4*)(W + kc * 128 + idx);
        }
        #pragma unroll
        for (int pass = 0; pass < 4; ++pass) {
            int r  = pass * 32 + (tid >> 3);
            int k4 = (tid & 7) * 4;
            int gr = brow + r; if (gr >= NN) gr = NN - 1;
            float4 hv = *(const float4*)(h + (size_t)gr * F + kc + k4);
            HsT[k4 + 0][r] = hv.x;
            HsT[k4 + 1][r] = hv.y;
            HsT[k4 + 2][r] = hv.z;
            HsT[k4 + 3][r] = hv.w;
        }
        __syncthreads();
        #pragma unroll
        for (int k = 0; k < 32; ++k) {
            float4 h0 = *(const float4*)(&HsT[k][r0]);
            float4 h1 = *(const float4*)(&HsT[k][r0 + 4]);
            float4 w0 = *(const float4*)(&Ws[k][c0]);
            float4 w1 = *(const float4*)(&Ws[k][c0 + 4]);
            float hr[8] = {h0.x, h0.y, h0.z, h0.w, h1.x, h1.y, h1.z, h1.w};
            float wc[8] = {w0.x, w0.y, w0.z, w0.w, w1.x, w1.y, w1.z, w1.w};
            #pragma unroll
            for (int r = 0; r < 8; ++r)
                #pragma unroll
                for (int c = 0; c < 8; ++c)
                    acc[r][c] += hr[r] * wc[c];
        }
        __syncthreads();
    }
    #pragma unroll
    for (int r = 0; r < 8; ++r) {
        int gr = brow + r0 + r;
        if (gr < NN) {
            *(float4*)(out + (size_t)gr * F + c0) =
                make_float4(acc[r][0], acc[r][1], acc[r][2], acc[r][3]);
            *(float4*)(out + (size_t)gr * F + c0 + 4) =
                make_float4(acc[r][4], acc[r][5], acc[r][6], acc[r][7]);
        }
    }
}

// ---------------- fp32 GEMM 128x32 (final layer), 4x8 tile, BR=256 --------------
__global__ __launch_bounds__(256) void k_gemm32(const float* __restrict__ h,
        const float* __restrict__ W, float* __restrict__ out) {
    constexpr int NC = FO, BR = 256, KC = 32;
    __shared__ float Ws[KC * NC];
    __shared__ float HsT[KC][BR + 4];
    const int tid  = threadIdx.x;
    const int c0   = (tid % 4) * 8;
    const int r0   = (tid / 4) * 4;
    const int brow = blockIdx.x * BR;
    float acc[4][8];
    #pragma unroll
    for (int r = 0; r < 4; ++r)
        #pragma unroll
        for (int c = 0; c < 8; ++c) acc[r][c] = 0.f;

    for (int kc = 0; kc < F; kc += KC) {
        for (int idx = tid * 4; idx < KC * NC; idx += 1024)
            *(float4*)(Ws + idx) = *(const float4*)(W + kc * NC + idx);
        #pragma unroll
        for (int pass = 0; pass < BR / 32; ++pass) {
            int r  = pass * 32 + tid / 8;
            int k4 = (tid % 8) * 4;
            int gr = brow + r; if (gr >= NN) gr = NN - 1;
            float4 hv = *(const float4*)(h + (size_t)gr * F + kc + k4);
            HsT[k4 + 0][r] = hv.x;
            HsT[k4 + 1][r] = hv.y;
            HsT[k4 + 2][r] = hv.z;
            HsT[k4 + 3][r] = hv.w;
        }
        __syncthreads();
        #pragma unroll
        for (int k = 0; k < KC; ++k) {
            float4 hv = *(const float4*)(&HsT[k][r0]);
            float4 wa = *(const float4*)(Ws + k * NC + c0);
            float4 wb = *(const float4*)(Ws + k * NC + c0 + 4);
            float hr[4] = {hv.x, hv.y, hv.z, hv.w};
            float wc[8] = {wa.x, wa.y, wa.z, wa.w, wb.x, wb.y, wb.z, wb.w};
            #pragma unroll
            for (int r = 0; r < 4; ++r)
                #pragma unroll
                for (int c = 0; c < 8; ++c)
                    acc[r][c] += hr[r] * wc[c];
        }
        __syncthreads();
    }
    #pragma unroll
    for (int r = 0; r < 4; ++r) {
        int gr = brow + r0 + r;
        if (gr < NN) {
            *(float4*)(out + (size_t)gr * NC + c0) =
                make_float4(acc[r][0], acc[r][1], acc[r][2], acc[r][3]);
            *(float4*)(out + (size_t)gr * NC + c0 + 4) =
                make_float4(acc[r][4], acc[r][5], acc[r][6], acc[r][7]);
        }
    }
}

// ---------------- aggregation d=128: float4 lanes, 2 rows/instr, 8 in flight ----
// MODE 0: mean  -> relu(s[v] + agg/max(deg,1) + b)
// MODE 1: gcn   -> relu((agg + g[v])/(deg+1) + b)
template<int MODE>
__global__ __launch_bounds__(256) void k_agg128(const float* __restrict__ g,
        const float* __restrict__ s, const int* __restrict__ offs,
        const int* __restrict__ csr, const float* __restrict__ degf,
        const float* __restrict__ b, float* __restrict__ out) {
    const int wid  = (int)((blockIdx.x * 256 + threadIdx.x) >> 6);
    const int lane = threadIdx.x & 63;
    if (wid >= NN) return;
    const int half = lane >> 5;         // which of 2 rows this lane loads
    const int li   = lane & 31;         // float4 slot within the 512B row
    const int beg = offs[wid], end = offs[wid + 1];
    const float4* g4 = (const float4*)g;
    float4 a0 = make_float4(0, 0, 0, 0), a1 = a0, a2 = a0, a3 = a0;
    int e = beg;
    for (; e + 7 < end; e += 8) {       // 8 rows in flight (4 loads x 2 rows)
        int u0 = csr[e + half];
        int u1 = csr[e + 2 + half];
        int u2 = csr[e + 4 + half];
        int u3 = csr[e + 6 + half];
        float4 v0 = g4[(size_t)u0 * 32 + li];
        float4 v1 = g4[(size_t)u1 * 32 + li];
        float4 v2 = g4[(size_t)u2 * 32 + li];
        float4 v3 = g4[(size_t)u3 * 32 + li];
        a0.x += v0.x; a0.y += v0.y; a0.z += v0.z; a0.w += v0.w;
        a1.x += v1.x; a1.y += v1.y; a1.z += v1.z; a1.w += v1.w;
        a2.x += v2.x; a2.y += v2.y; a2.z += v2.z; a2.w += v2.w;
        a3.x += v3.x; a3.y += v3.y; a3.z += v3.z; a3.w += v3.w;
    }
    for (; e + 1 < end; e += 2) {
        int u = csr[e + half];
        float4 v = g4[(size_t)u * 32 + li];
        a0.x += v.x; a0.y += v.y; a0.z += v.z; a0.w += v.w;
    }
    if (e < end && half == 0) {         // odd tail: half 0 only
        float4 v = g4[(size_t)csr[e] * 32 + li];
        a0.x += v.x; a0.y += v.y; a0.z += v.z; a0.w += v.w;
    }
    a0.x += a1.x + a2.x + a3.x; a0.y += a1.y + a2.y + a3.y;
    a0.z += a1.z + a2.z + a3.z; a0.w += a1.w + a2.w + a3.w;
    // combine the two halves (all lanes participate, then half 1 retires)
    a0.x += __shfl_xor(a0.x, 32, 64);
    a0.y += __shfl_xor(a0.y, 32, 64);
    a0.z += __shfl_xor(a0.z, 32, 64);
    a0.w += __shfl_xor(a0.w, 32, 64);
    if (half) return;
    const float dg = degf[wid];
    float4 bb = ((const float4*)b)[li];
    float4 r;
    if (MODE == 0) {
        float inv = 1.f / fmaxf(dg, 1.f);
        float4 sv = ((const float4*)s)[(size_t)wid * 32 + li];
        r.x = fmaxf(sv.x + a0.x * inv + bb.x, 0.f);
        r.y = fmaxf(sv.y + a0.y * inv + bb.y, 0.f);
        r.z = fmaxf(sv.z + a0.z * inv + bb.z, 0.f);
        r.w = fmaxf(sv.w + a0.w * inv + bb.w, 0.f);
    } else {
        float inv = 1.f / (dg + 1.f);
        float4 gv = g4[(size_t)wid * 32 + li];
        r.x = fmaxf((a0.x + gv.x) * inv + bb.x, 0.f);
        r.y = fmaxf((a0.y + gv.y) * inv + bb.y, 0.f);
        r.z = fmaxf((a0.z + gv.z) * inv + bb.z, 0.f);
        r.w = fmaxf((a0.w + gv.w) * inv + bb.w, 0.f);
    }
    ((float4*)out)[(size_t)wid * 32 + li] = r;
}

// ---------------- aggregation d=32 (mean, no relu): 8 rows/instr ----------------
__global__ __launch_bounds__(256) void k_agg32(const float* __restrict__ g,
        const float* __restrict__ s, const int* __restrict__ offs,
        const int* __restrict__ csr, const float* __restrict__ degf,
        const float* __restrict__ b, float* __restrict__ out) {
    const int wid  = (int)((blockIdx.x * 256 + threadIdx.x) >> 6);
    const int lane = threadIdx.x & 63;
    if (wid >= NN) return;
    const int grp = lane >> 3;          // 8 groups, one row each
    const int li  = lane & 7;           // float4 slot within the 128B row
    const int beg = offs[wid], end = offs[wid + 1];
    const float4* g4 = (const float4*)g;
    float4 a0 = make_float4(0, 0, 0, 0), a1 = a0;
    int e = beg + grp;
    for (; e + 8 < end; e += 16) {
        int u0 = csr[e], u1 = csr[e + 8];
        float4 v0 = g4[(size_t)u0 * 8 + li];
        float4 v1 = g4[(size_t)u1 * 8 + li];
        a0.x += v0.x; a0.y += v0.y; a0.z += v0.z; a0.w += v0.w;
        a1.x += v1.x; a1.y += v1.y; a1.z += v1.z; a1.w += v1.w;
    }
    if (e < end) {
        float4 v = g4[(size_t)csr[e] * 8 + li];
        a0.x += v.x; a0.y += v.y; a0.z += v.z; a0.w += v.w;
    }
    a0.x += a1.x; a0.y += a1.y; a0.z += a1.z; a0.w += a1.w;
    #pragma unroll
    for (int d = 8; d < 64; d <<= 1) {
        a0.x += __shfl_xor(a0.x, d, 64);
        a0.y += __shfl_xor(a0.y, d, 64);
        a0.z += __shfl_xor(a0.z, d, 64);
        a0.w += __shfl_xor(a0.w, d, 64);
    }
    if (grp) return;
    const float inv = 1.f / fmaxf(degf[wid], 1.f);
    float4 bb = ((const float4*)b)[li];
    float4 sv = ((const float4*)s)[(size_t)wid * 8 + li];
    float4 r;
    r.x = sv.x + a0.x * inv + bb.x;
    r.y = sv.y + a0.y * inv + bb.y;
    r.z = sv.z + a0.z * inv + bb.z;
    r.w = sv.w + a0.w * inv + bb.w;
    ((float4*)out)[(size_t)wid * 8 + li] = r;
}

extern "C" void kernel_launch(void* const* d_in, const int* in_sizes, int n_in,
                              void* d_out, int out_size, void* d_ws, size_t ws_size,
                              hipStream_t stream) {
    const float* x       = (const float*)d_in[0];
    const int*   src     = (const int*)  d_in[1];
    const int*   dst     = (const int*)  d_in[2];
    const float* Wself0  = (const float*)d_in[3];
    const float* Wneigh0 = (const float*)d_in[4];
    const float* b0      = (const float*)d_in[5];
    const float* Wneigh1 = (const float*)d_in[6];
    const float* b1      = (const float*)d_in[7];
    const float* Wneigh2 = (const float*)d_in[8];
    const float* b2      = (const float*)d_in[9];
    const float* Wself3  = (const float*)d_in[10];
    const float* Wneigh3 = (const float*)d_in[11];
    const float* b3      = (const float*)d_in[12];
    float* out = (float*)d_out;

    char* ws = (char*)d_ws;
    size_t off = 0;
    auto alloc = [&](size_t bytes) -> void* {
        void* p = ws + off;
        off += (bytes + 255) & ~(size_t)255;
        return p;
    };
    int*   degi   = (int*)  alloc((size_t)NN * 4);
    float* degf   = (float*)alloc((size_t)NN * 4);
    int*   offs   = (int*)  alloc((size_t)(NN + 1) * 4);
    int*   cursor = (int*)  alloc((size_t)(NN + 1) * 4);
    int*   csr    = (int*)  alloc((size_t)NE * 4);
    int*   bsum   = (int*)  alloc((size_t)NB * 4);
    int*   bpre   = (int*)  alloc((size_t)NB * 4);
    float* bufh   = (float*)alloc((size_t)NN * F * 4);
    float* bufg   = (float*)alloc((size_t)NN * F * 4);
    float* bufs   = (float*)alloc((size_t)NN * F * 4);

    hipMemsetAsync(degi, 0, (size_t)NN * 4, stream);

    const int egrid = (NE + 255) / 256;
    const int wgrid = (NN + 3) / 4;           // one wave per node
    const int g128  = (NN + 127) / 128;
    const int g32   = (NN + 255) / 256;

    k_deg     <<<egrid, 256, 0, stream>>>(dst, degi);
    k_bsum    <<<NB, 1024, 0, stream>>>(degi, degf, bsum);
    k_bscan   <<<1, 64, 0, stream>>>(bsum, bpre, offs);
    k_bscatter<<<NB, 1024, 0, stream>>>(degi, bpre, offs, cursor);
    k_fill    <<<egrid, 256, 0, stream>>>(src, dst, cursor, csr);
    k_l2norm  <<<wgrid, 256, 0, stream>>>(x, bufh);

    // layer 0 (mean): transform-then-aggregate (linearity of segment_sum)
    k_gemm128<<<g128, 256, 0, stream>>>(bufh, Wself0, bufs);
    k_gemm128<<<g128, 256, 0, stream>>>(bufh, Wneigh0, bufg);
    k_agg128<0><<<wgrid, 256, 0, stream>>>(bufg, bufs, offs, csr, degf, b0, bufh);

    // layer 1 (gcn)
    k_gemm128<<<g128, 256, 0, stream>>>(bufh, Wneigh1, bufg);
    k_agg128<1><<<wgrid, 256, 0, stream>>>(bufg, nullptr, offs, csr, degf, b1, bufh);

    // layer 2 (gcn)
    k_gemm128<<<g128, 256, 0, stream>>>(bufh, Wneigh2, bufg);
    k_agg128<1><<<wgrid, 256, 0, stream>>>(bufg, nullptr, offs, csr, degf, b2, bufh);

    // layer 3 (mean, 128->32): aggregate AFTER transform => 4x less gather traffic
    k_gemm32<<<g32, 256, 0, stream>>>(bufh, Wself3, bufs);
    k_gemm32<<<g32, 256, 0, stream>>>(bufh, Wneigh3, bufg);
    k_agg32 <<<wgrid, 256, 0, stream>>>(bufg, bufs, offs, csr, degf, b3, out);
}

// Round 4
// 470.253 us; speedup vs baseline: 1.3403x; 1.1358x over previous
//
#include <hip/hip_runtime.h>

#define NN 50000
#define NE 800000
#define F  128
#define FO 32
#define NB 49   // ceil(NN/1024)

typedef _Float16 h16;
typedef h16   half8 __attribute__((ext_vector_type(8)));
typedef h16   h16x4 __attribute__((ext_vector_type(4)));
typedef h16   h16x2 __attribute__((ext_vector_type(2)));
typedef float f32x4 __attribute__((ext_vector_type(4)));

// ---------------- degree histogram ----------------
__global__ void k_deg(const int* __restrict__ dst, int* __restrict__ degi) {
    int e = blockIdx.x * 256 + threadIdx.x;
    if (e < NE) atomicAdd(&degi[dst[e]], 1);
}

// ---------------- parallel scan, stage 1: per-block sums (+degf) ----------------
__global__ __launch_bounds__(1024) void k_bsum(const int* __restrict__ degi,
        float* __restrict__ degf, int* __restrict__ bsum) {
    const int tid  = threadIdx.x;
    const int lane = tid & 63;
    const int wv   = tid >> 6;
    int i = blockIdx.x * 1024 + tid;
    int v = (i < NN) ? degi[i] : 0;
    if (i < NN) degf[i] = (float)v;
    int s = v;
    #pragma unroll
    for (int d = 1; d < 64; d <<= 1) s += __shfl_xor(s, d, 64);
    __shared__ int ws[16];
    if (lane == 0) ws[wv] = s;
    __syncthreads();
    if (tid < 16) {
        int t = ws[tid];
        #pragma unroll
        for (int d = 1; d < 16; d <<= 1) t += __shfl_xor(t, d, 64);
        if (tid == 0) bsum[blockIdx.x] = t;
    }
}

// ---------------- scan stage 2: scan 49 block sums (one wave) ----------------
__global__ void k_bscan(const int* __restrict__ bsum, int* __restrict__ bpre,
                        int* __restrict__ offs) {
    int lane = threadIdx.x;
    int v = (lane < NB) ? bsum[lane] : 0;
    int incl = v;
    #pragma unroll
    for (int d = 1; d < 64; d <<= 1) {
        int t = __shfl_up(incl, d, 64);
        if (lane >= d) incl += t;
    }
    if (lane < NB) bpre[lane] = incl - v;
    if (lane == 63) offs[NN] = incl;
}

// ---------------- scan stage 3: scatter exclusive offsets ----------------
__global__ __launch_bounds__(1024) void k_bscatter(const int* __restrict__ degi,
        const int* __restrict__ bpre, int* __restrict__ offs, int* __restrict__ cursor) {
    const int tid  = threadIdx.x;
    const int lane = tid & 63;
    const int wv   = tid >> 6;
    int i = blockIdx.x * 1024 + tid;
    int v = (i < NN) ? degi[i] : 0;
    int incl = v;
    #pragma unroll
    for (int d = 1; d < 64; d <<= 1) {
        int t = __shfl_up(incl, d, 64);
        if (lane >= d) incl += t;
    }
    __shared__ int wsum[16];
    __shared__ int wpre[16];
    if (lane == 63) wsum[wv] = incl;
    __syncthreads();
    if (tid == 0) {
        int run = 0;
        #pragma unroll
        for (int w = 0; w < 16; ++w) { wpre[w] = run; run += wsum[w]; }
    }
    __syncthreads();
    if (i < NN) {
        int excl = bpre[blockIdx.x] + wpre[wv] + incl - v;
        offs[i]   = excl;
        cursor[i] = excl;
    }
}

// ---------------- CSR fill ----------------
__global__ void k_fill(const int* __restrict__ src, const int* __restrict__ dst,
                       int* __restrict__ cursor, int* __restrict__ csr) {
    int e = blockIdx.x * 256 + threadIdx.x;
    if (e < NE) {
        int p = atomicAdd(&cursor[dst[e]], 1);
        csr[p] = src[e];
    }
}

// ---------------- weight prep: fp32 W[K=128][NC] -> fragment-ordered fp16 hi/lo --
// B-frag layout for mfma_f32_16x16x32_f16: col n = ct*16 + (lane&15),
// k = kt*32 + (lane>>4)*8 + j  (8 contiguous-k elems per lane => one 16B load).
// Wf flat index: (((part*4 + kt)*NCT + ct)*64 + lane)*8 + j, part 0=hi 1=lo.
template<int NC>
__global__ __launch_bounds__(256) void k_wprep(const float* __restrict__ W,
                                               h16* __restrict__ Wf) {
    constexpr int NCT = NC / 16;
    int idx = blockIdx.x * 256 + threadIdx.x;
    if (idx >= 128 * NC) return;
    int k = idx / NC, n = idx % NC;
    int kt = k >> 5, g = (k & 31) >> 3, j = k & 7;
    int ct = n >> 4;
    int lane = g * 16 + (n & 15);
    float w = W[idx];
    h16 hi = (h16)w;
    h16 lo = (h16)(w - (float)hi);
    int base = ((kt * NCT + ct) * 64 + lane) * 8 + j;
    Wf[base] = hi;
    Wf[base + NCT * 2048] = lo;   // part stride = 4*NCT*64*8
}

// ---------------- row L2 normalize -> split fp16 hi/lo ----------------
__global__ __launch_bounds__(256) void k_l2norm(const float* __restrict__ x,
        h16* __restrict__ hhi, h16* __restrict__ hlo) {
    const int wid  = (int)((blockIdx.x * 256 + threadIdx.x) >> 6);
    const int lane = threadIdx.x & 63;
    if (wid >= NN) return;
    const float2* xr = (const float2*)(x + (size_t)wid * F);
    float2 v = xr[lane];
    float ss = v.x * v.x + v.y * v.y;
    #pragma unroll
    for (int d = 1; d < 64; d <<= 1) ss += __shfl_xor(ss, d, 64);
    float inv = 1.0f / fmaxf(sqrtf(ss), 1e-12f);
    float ox = v.x * inv, oy = v.y * inv;
    h16 hx = (h16)ox, hy = (h16)oy;
    h16x2 vhi = {hx, hy};
    h16x2 vlo = {(h16)(ox - (float)hx), (h16)(oy - (float)hy)};
    *(h16x2*)(hhi + (size_t)wid * F + lane * 2) = vhi;
    *(h16x2*)(hlo + (size_t)wid * F + lane * 2) = vlo;
}

// ---------------- fp16-split MFMA GEMM: out = h @ W (fp32 result) ----------------
// h given as hi+lo fp16 [NN][128]; error ~2^-22 (Ootomo 3-term split).
// One wave = 16 rows; A-frags (8x16B) straight from global; B-frags from
// pre-permuted Wf (L2-resident). No LDS.
template<int NCT>
__device__ __forceinline__ void mfma_cols(const half8* Ahi, const half8* Alo,
        const h16* __restrict__ Wf, float* __restrict__ out, int row0, int l) {
    const int cdc = l & 15;          // C/D: col = lane&15
    const int cdr = (l >> 4) * 4;    //      row = (lane>>4)*4 + reg   [m89]
    #pragma unroll
    for (int ct = 0; ct < NCT; ++ct) {
        f32x4 acc = {0.f, 0.f, 0.f, 0.f};
        #pragma unroll
        for (int kt = 0; kt < 4; ++kt) {
            half8 bh = *(const half8*)(Wf + (size_t)(((kt * NCT + ct) * 64 + l) * 8));
            half8 bl = *(const half8*)(Wf + (size_t)((((4 + kt) * NCT + ct) * 64 + l) * 8));
            acc = __builtin_amdgcn_mfma_f32_16x16x32_f16(Ahi[kt], bh, acc, 0, 0, 0);
            acc = __builtin_amdgcn_mfma_f32_16x16x32_f16(Alo[kt], bh, acc, 0, 0, 0);
            acc = __builtin_amdgcn_mfma_f32_16x16x32_f16(Ahi[kt], bl, acc, 0, 0, 0);
        }
        #pragma unroll
        for (int r = 0; r < 4; ++r) {
            int gr = row0 + cdr + r;
            if (gr < NN) out[(size_t)gr * (NCT * 16) + ct * 16 + cdc] = acc[r];
        }
    }
}

template<int NCTA, int NCTB>
__global__ __launch_bounds__(256) void k_mfma(const h16* __restrict__ hhi,
        const h16* __restrict__ hlo, const h16* __restrict__ WfA,
        const h16* __restrict__ WfB, float* __restrict__ outA,
        float* __restrict__ outB) {
    const int tid = threadIdx.x;
    const int l   = tid & 63;
    const int wv  = tid >> 6;
    const int row0 = blockIdx.x * 64 + wv * 16;
    int ar = row0 + (l & 15); if (ar >= NN) ar = NN - 1;   // A: row = lane&15
    const size_t ab = (size_t)ar * F + (l >> 4) * 8;       //    k = kt*32+(lane>>4)*8+j
    half8 Ahi[4], Alo[4];
    #pragma unroll
    for (int kt = 0; kt < 4; ++kt) {
        Ahi[kt] = *(const half8*)(hhi + ab + kt * 32);
        Alo[kt] = *(const half8*)(hlo + ab + kt * 32);
    }
    mfma_cols<NCTA>(Ahi, Alo, WfA, outA, row0, l);
    if constexpr (NCTB > 0) mfma_cols<NCTB>(Ahi, Alo, WfB, outB, row0, l);
}

// ---------------- aggregation d=128 -> split fp16 h output ----------------
// MODE 0: mean  -> relu(s[v] + agg/max(deg,1) + b)
// MODE 1: gcn   -> relu((agg + g[v])/(deg+1) + b)
template<int MODE>
__global__ __launch_bounds__(256) void k_agg128(const float* __restrict__ g,
        const float* __restrict__ s, const int* __restrict__ offs,
        const int* __restrict__ csr, const float* __restrict__ degf,
        const float* __restrict__ b, h16* __restrict__ hhi, h16* __restrict__ hlo) {
    const int wid  = (int)((blockIdx.x * 256 + threadIdx.x) >> 6);
    const int lane = threadIdx.x & 63;
    if (wid >= NN) return;
    const int half = lane >> 5;
    const int li   = lane & 31;
    const int beg = offs[wid], end = offs[wid + 1];
    const float4* g4 = (const float4*)g;
    float4 a0 = make_float4(0, 0, 0, 0), a1 = a0, a2 = a0, a3 = a0;
    int e = beg;
    for (; e + 7 < end; e += 8) {
        int u0 = csr[e + half];
        int u1 = csr[e + 2 + half];
        int u2 = csr[e + 4 + half];
        int u3 = csr[e + 6 + half];
        float4 v0 = g4[(size_t)u0 * 32 + li];
        float4 v1 = g4[(size_t)u1 * 32 + li];
        float4 v2 = g4[(size_t)u2 * 32 + li];
        float4 v3 = g4[(size_t)u3 * 32 + li];
        a0.x += v0.x; a0.y += v0.y; a0.z += v0.z; a0.w += v0.w;
        a1.x += v1.x; a1.y += v1.y; a1.z += v1.z; a1.w += v1.w;
        a2.x += v2.x; a2.y += v2.y; a2.z += v2.z; a2.w += v2.w;
        a3.x += v3.x; a3.y += v3.y; a3.z += v3.z; a3.w += v3.w;
    }
    for (; e + 1 < end; e += 2) {
        int u = csr[e + half];
        float4 v = g4[(size_t)u * 32 + li];
        a0.x += v.x; a0.y += v.y; a0.z += v.z; a0.w += v.w;
    }
    if (e < end && half == 0) {
        float4 v = g4[(size_t)csr[e] * 32 + li];
        a0.x += v.x; a0.y += v.y; a0.z += v.z; a0.w += v.w;
    }
    a0.x += a1.x + a2.x + a3.x; a0.y += a1.y + a2.y + a3.y;
    a0.z += a1.z + a2.z + a3.z; a0.w += a1.w + a2.w + a3.w;
    a0.x += __shfl_xor(a0.x, 32, 64);
    a0.y += __shfl_xor(a0.y, 32, 64);
    a0.z += __shfl_xor(a0.z, 32, 64);
    a0.w += __shfl_xor(a0.w, 32, 64);
    if (half) return;
    const float dg = degf[wid];
    float4 bb = ((const float4*)b)[li];
    float4 r;
    if (MODE == 0) {
        float inv = 1.f / fmaxf(dg, 1.f);
        float4 sv = ((const float4*)s)[(size_t)wid * 32 + li];
        r.x = fmaxf(sv.x + a0.x * inv + bb.x, 0.f);
        r.y = fmaxf(sv.y + a0.y * inv + bb.y, 0.f);
        r.z = fmaxf(sv.z + a0.z * inv + bb.z, 0.f);
        r.w = fmaxf(sv.w + a0.w * inv + bb.w, 0.f);
    } else {
        float inv = 1.f / (dg + 1.f);
        float4 gv = g4[(size_t)wid * 32 + li];
        r.x = fmaxf((a0.x + gv.x) * inv + bb.x, 0.f);
        r.y = fmaxf((a0.y + gv.y) * inv + bb.y, 0.f);
        r.z = fmaxf((a0.z + gv.z) * inv + bb.z, 0.f);
        r.w = fmaxf((a0.w + gv.w) * inv + bb.w, 0.f);
    }
    h16 p0 = (h16)r.x, p1 = (h16)r.y, p2 = (h16)r.z, p3 = (h16)r.w;
    h16x4 vhi = {p0, p1, p2, p3};
    h16x4 vlo = {(h16)(r.x - (float)p0), (h16)(r.y - (float)p1),
                 (h16)(r.z - (float)p2), (h16)(r.w - (float)p3)};
    *(h16x4*)(hhi + (size_t)wid * F + li * 4) = vhi;
    *(h16x4*)(hlo + (size_t)wid * F + li * 4) = vlo;
}

// ---------------- aggregation d=32 (mean, no relu, fp32 out) ----------------
__global__ __launch_bounds__(256) void k_agg32(const float* __restrict__ g,
        const float* __restrict__ s, const int* __restrict__ offs,
        const int* __restrict__ csr, const float* __restrict__ degf,
        const float* __restrict__ b, float* __restrict__ out) {
    const int wid  = (int)((blockIdx.x * 256 + threadIdx.x) >> 6);
    const int lane = threadIdx.x & 63;
    if (wid >= NN) return;
    const int grp = lane >> 3;
    const int li  = lane & 7;
    const int beg = offs[wid], end = offs[wid + 1];
    const float4* g4 = (const float4*)g;
    float4 a0 = make_float4(0, 0, 0, 0), a1 = a0;
    int e = beg + grp;
    for (; e + 8 < end; e += 16) {
        int u0 = csr[e], u1 = csr[e + 8];
        float4 v0 = g4[(size_t)u0 * 8 + li];
        float4 v1 = g4[(size_t)u1 * 8 + li];
        a0.x += v0.x; a0.y += v0.y; a0.z += v0.z; a0.w += v0.w;
        a1.x += v1.x; a1.y += v1.y; a1.z += v1.z; a1.w += v1.w;
    }
    if (e < end) {
        float4 v = g4[(size_t)csr[e] * 8 + li];
        a0.x += v.x; a0.y += v.y; a0.z += v.z; a0.w += v.w;
    }
    a0.x += a1.x; a0.y += a1.y; a0.z += a1.z; a0.w += a1.w;
    #pragma unroll
    for (int d = 8; d < 64; d <<= 1) {
        a0.x += __shfl_xor(a0.x, d, 64);
        a0.y += __shfl_xor(a0.y, d, 64);
        a0.z += __shfl_xor(a0.z, d, 64);
        a0.w += __shfl_xor(a0.w, d, 64);
    }
    if (grp) return;
    const float inv = 1.f / fmaxf(degf[wid], 1.f);
    float4 bb = ((const float4*)b)[li];
    float4 sv = ((const float4*)s)[(size_t)wid * 8 + li];
    float4 r;
    r.x = sv.x + a0.x * inv + bb.x;
    r.y = sv.y + a0.y * inv + bb.y;
    r.z = sv.z + a0.z * inv + bb.z;
    r.w = sv.w + a0.w * inv + bb.w;
    ((float4*)out)[(size_t)wid * 8 + li] = r;
}

extern "C" void kernel_launch(void* const* d_in, const int* in_sizes, int n_in,
                              void* d_out, int out_size, void* d_ws, size_t ws_size,
                              hipStream_t stream) {
    const float* x       = (const float*)d_in[0];
    const int*   src     = (const int*)  d_in[1];
    const int*   dst     = (const int*)  d_in[2];
    const float* Wself0  = (const float*)d_in[3];
    const float* Wneigh0 = (const float*)d_in[4];
    const float* b0      = (const float*)d_in[5];
    const float* Wneigh1 = (const float*)d_in[6];
    const float* b1      = (const float*)d_in[7];
    const float* Wneigh2 = (const float*)d_in[8];
    const float* b2      = (const float*)d_in[9];
    const float* Wself3  = (const float*)d_in[10];
    const float* Wneigh3 = (const float*)d_in[11];
    const float* b3      = (const float*)d_in[12];
    float* out = (float*)d_out;

    char* ws = (char*)d_ws;
    size_t off = 0;
    auto alloc = [&](size_t bytes) -> void* {
        void* p = ws + off;
        off += (bytes + 255) & ~(size_t)255;
        return p;
    };
    int*   degi   = (int*)  alloc((size_t)NN * 4);
    float* degf   = (float*)alloc((size_t)NN * 4);
    int*   offs   = (int*)  alloc((size_t)(NN + 1) * 4);
    int*   cursor = (int*)  alloc((size_t)(NN + 1) * 4);
    int*   csr    = (int*)  alloc((size_t)NE * 4);
    int*   bsum   = (int*)  alloc((size_t)NB * 4);
    int*   bpre   = (int*)  alloc((size_t)NB * 4);
    h16*   hhi    = (h16*)  alloc((size_t)NN * F * 2);
    h16*   hlo    = (h16*)  alloc((size_t)NN * F * 2);
    float* bufg   = (float*)alloc((size_t)NN * F * 4);
    float* bufs   = (float*)alloc((size_t)NN * F * 4);
    h16*   WfS0   = (h16*)  alloc((size_t)128 * 128 * 2 * 2);
    h16*   WfN0   = (h16*)  alloc((size_t)128 * 128 * 2 * 2);
    h16*   WfN1   = (h16*)  alloc((size_t)128 * 128 * 2 * 2);
    h16*   WfN2   = (h16*)  alloc((size_t)128 * 128 * 2 * 2);
    h16*   WfS3   = (h16*)  alloc((size_t)128 * 32 * 2 * 2);
    h16*   WfN3   = (h16*)  alloc((size_t)128 * 32 * 2 * 2);

    hipMemsetAsync(degi, 0, (size_t)NN * 4, stream);

    const int egrid = (NE + 255) / 256;
    const int wgrid = (NN + 3) / 4;           // one wave per node
    const int mgrid = (NN + 63) / 64;         // 64 rows per block (4 waves x 16)

    // weight prep (tiny; independent of graph prep)
    k_wprep<128><<<64, 256, 0, stream>>>(Wself0,  WfS0);
    k_wprep<128><<<64, 256, 0, stream>>>(Wneigh0, WfN0);
    k_wprep<128><<<64, 256, 0, stream>>>(Wneigh1, WfN1);
    k_wprep<128><<<64, 256, 0, stream>>>(Wneigh2, WfN2);
    k_wprep<32> <<<16, 256, 0, stream>>>(Wself3,  WfS3);
    k_wprep<32> <<<16, 256, 0, stream>>>(Wneigh3, WfN3);

    k_deg     <<<egrid, 256, 0, stream>>>(dst, degi);
    k_bsum    <<<NB, 1024, 0, stream>>>(degi, degf, bsum);
    k_bscan   <<<1, 64, 0, stream>>>(bsum, bpre, offs);
    k_bscatter<<<NB, 1024, 0, stream>>>(degi, bpre, offs, cursor);
    k_fill    <<<egrid, 256, 0, stream>>>(src, dst, cursor, csr);
    k_l2norm  <<<wgrid, 256, 0, stream>>>(x, hhi, hlo);

    // layer 0 (mean): fused self+neigh MFMA GEMM, then aggregate
    k_mfma<8, 8><<<mgrid, 256, 0, stream>>>(hhi, hlo, WfS0, WfN0, bufs, bufg);
    k_agg128<0><<<wgrid, 256, 0, stream>>>(bufg, bufs, offs, csr, degf, b0, hhi, hlo);

    // layer 1 (gcn)
    k_mfma<8, 0><<<mgrid, 256, 0, stream>>>(hhi, hlo, WfN1, nullptr, bufg, nullptr);
    k_agg128<1><<<wgrid, 256, 0, stream>>>(bufg, nullptr, offs, csr, degf, b1, hhi, hlo);

    // layer 2 (gcn)
    k_mfma<8, 0><<<mgrid, 256, 0, stream>>>(hhi, hlo, WfN2, nullptr, bufg, nullptr);
    k_agg128<1><<<wgrid, 256, 0, stream>>>(bufg, nullptr, offs, csr, degf, b2, hhi, hlo);

    // layer 3 (mean, 128->32): fused self+neigh, aggregate after transform
    k_mfma<2, 2><<<mgrid, 256, 0, stream>>>(hhi, hlo, WfS3, WfN3, bufs, bufg);
    k_agg32<<<wgrid, 256, 0, stream>>>(bufg, bufs, offs, csr, degf, b3, out);
}

// Round 5
// 389.670 us; speedup vs baseline: 1.6175x; 1.2068x over previous
//
#include <hip/hip_runtime.h>

#define NN 50000
#define NE 800000
#define F  128
#define FO 32
#define NB 49   // ceil(NN/1024)

typedef _Float16 h16;
typedef h16   half8 __attribute__((ext_vector_type(8)));
typedef h16   h16x2 __attribute__((ext_vector_type(2)));
typedef float f32x4 __attribute__((ext_vector_type(4)));

// ---------------- degree histogram ----------------
__global__ void k_deg(const int* __restrict__ dst, int* __restrict__ degi) {
    int e = blockIdx.x * 256 + threadIdx.x;
    if (e < NE) atomicAdd(&degi[dst[e]], 1);
}

// ---------------- parallel scan, stage 1: per-block sums (+degf) ----------------
__global__ __launch_bounds__(1024) void k_bsum(const int* __restrict__ degi,
        float* __restrict__ degf, int* __restrict__ bsum) {
    const int tid  = threadIdx.x;
    const int lane = tid & 63;
    const int wv   = tid >> 6;
    int i = blockIdx.x * 1024 + tid;
    int v = (i < NN) ? degi[i] : 0;
    if (i < NN) degf[i] = (float)v;
    int s = v;
    #pragma unroll
    for (int d = 1; d < 64; d <<= 1) s += __shfl_xor(s, d, 64);
    __shared__ int ws[16];
    if (lane == 0) ws[wv] = s;
    __syncthreads();
    if (tid < 16) {
        int t = ws[tid];
        #pragma unroll
        for (int d = 1; d < 16; d <<= 1) t += __shfl_xor(t, d, 64);
        if (tid == 0) bsum[blockIdx.x] = t;
    }
}

// ---------------- scan stage 2: scan 49 block sums (one wave) ----------------
__global__ void k_bscan(const int* __restrict__ bsum, int* __restrict__ bpre,
                        int* __restrict__ offs) {
    int lane = threadIdx.x;
    int v = (lane < NB) ? bsum[lane] : 0;
    int incl = v;
    #pragma unroll
    for (int d = 1; d < 64; d <<= 1) {
        int t = __shfl_up(incl, d, 64);
        if (lane >= d) incl += t;
    }
    if (lane < NB) bpre[lane] = incl - v;
    if (lane == 63) offs[NN] = incl;
}

// ---------------- scan stage 3: scatter exclusive offsets ----------------
__global__ __launch_bounds__(1024) void k_bscatter(const int* __restrict__ degi,
        const int* __restrict__ bpre, int* __restrict__ offs, int* __restrict__ cursor) {
    const int tid  = threadIdx.x;
    const int lane = tid & 63;
    const int wv   = tid >> 6;
    int i = blockIdx.x * 1024 + tid;
    int v = (i < NN) ? degi[i] : 0;
    int incl = v;
    #pragma unroll
    for (int d = 1; d < 64; d <<= 1) {
        int t = __shfl_up(incl, d, 64);
        if (lane >= d) incl += t;
    }
    __shared__ int wsum[16];
    __shared__ int wpre[16];
    if (lane == 63) wsum[wv] = incl;
    __syncthreads();
    if (tid == 0) {
        int run = 0;
        #pragma unroll
        for (int w = 0; w < 16; ++w) { wpre[w] = run; run += wsum[w]; }
    }
    __syncthreads();
    if (i < NN) {
        int excl = bpre[blockIdx.x] + wpre[wv] + incl - v;
        offs[i]   = excl;
        cursor[i] = excl;
    }
}

// ---------------- CSR fill ----------------
__global__ void k_fill(const int* __restrict__ src, const int* __restrict__ dst,
                       int* __restrict__ cursor, int* __restrict__ csr) {
    int e = blockIdx.x * 256 + threadIdx.x;
    if (e < NE) {
        int p = atomicAdd(&cursor[dst[e]], 1);
        csr[p] = src[e];
    }
}

// ---------------- weight prep: fp32 W[K=128][NC] -> fragment-ordered fp16 hi/lo --
// B-frag layout for mfma_f32_16x16x32_f16: col n = ct*16 + (lane&15),
// k = kt*32 + (lane>>4)*8 + j  (8 contiguous-k elems per lane => one 16B load).
// Wf flat index: (((part*4 + kt)*NCT + ct)*64 + lane)*8 + j, part 0=hi 1=lo.
__device__ __forceinline__ void wprep_one(const float* __restrict__ W,
        h16* __restrict__ Wf, int idx, int NC, int NCT) {
    if (idx >= 128 * NC) return;
    int k = idx / NC, n = idx - k * NC;
    int kt = k >> 5, g = (k & 31) >> 3, j = k & 7;
    int ct = n >> 4;
    int lane = g * 16 + (n & 15);
    float w = W[idx];
    h16 hi = (h16)w;
    h16 lo = (h16)(w - (float)hi);
    int base = ((kt * NCT + ct) * 64 + lane) * 8 + j;
    Wf[base] = hi;
    Wf[base + NCT * 2048] = lo;   // part stride = 4*NCT*64*8
}

__global__ __launch_bounds__(256) void k_wprep_all(
        const float* __restrict__ S0, const float* __restrict__ N0,
        const float* __restrict__ N1, const float* __restrict__ N2,
        const float* __restrict__ S3, const float* __restrict__ N3,
        h16* fS0, h16* fN0, h16* fN1, h16* fN2, h16* fS3, h16* fN3) {
    int bb = blockIdx.x, tid = threadIdx.x;
    if (bb < 256) {
        const float* W = bb < 64 ? S0 : bb < 128 ? N0 : bb < 192 ? N1 : N2;
        h16*        Wf = bb < 64 ? fS0 : bb < 128 ? fN0 : bb < 192 ? fN1 : fN2;
        wprep_one(W, Wf, (bb & 63) * 256 + tid, 128, 8);
    } else {
        int b2 = bb - 256;
        const float* W = b2 < 16 ? S3 : N3;
        h16*        Wf = b2 < 16 ? fS3 : fN3;
        wprep_one(W, Wf, (b2 & 15) * 256 + tid, 32, 2);
    }
}

// ---------------- row L2 normalize -> split fp16 hi/lo ----------------
__global__ __launch_bounds__(256) void k_l2norm(const float* __restrict__ x,
        h16* __restrict__ hhi, h16* __restrict__ hlo) {
    const int wid  = (int)((blockIdx.x * 256 + threadIdx.x) >> 6);
    const int lane = threadIdx.x & 63;
    if (wid >= NN) return;
    const float2* xr = (const float2*)(x + (size_t)wid * F);
    float2 v = xr[lane];
    float ss = v.x * v.x + v.y * v.y;
    #pragma unroll
    for (int d = 1; d < 64; d <<= 1) ss += __shfl_xor(ss, d, 64);
    float inv = 1.0f / fmaxf(sqrtf(ss), 1e-12f);
    float ox = v.x * inv, oy = v.y * inv;
    h16 hx = (h16)ox, hy = (h16)oy;
    h16x2 vhi = {hx, hy};
    h16x2 vlo = {(h16)(ox - (float)hx), (h16)(oy - (float)hy)};
    *(h16x2*)(hhi + (size_t)wid * F + lane * 2) = vhi;
    *(h16x2*)(hlo + (size_t)wid * F + lane * 2) = vlo;
}

// ---------------- fp16-split MFMA GEMM: out = h @ W ----------------
// h given as hi+lo fp16 [NN][128]; error ~2^-22 (Ootomo 3-term split).
// One wave = 16 rows; A-frags straight from global; B-frags from pre-permuted
// Wf (L2-resident). No LDS. OUT16: emit fp16 (for the gather operand).
template<int NCT, bool OUT16>
__device__ __forceinline__ void mfma_cols(const half8* Ahi, const half8* Alo,
        const h16* __restrict__ Wf, void* __restrict__ out, int row0, int l) {
    const int cdc = l & 15;          // C/D: col = lane&15
    const int cdr = (l >> 4) * 4;    //      row = (lane>>4)*4 + reg   [m89]
    #pragma unroll
    for (int ct = 0; ct < NCT; ++ct) {
        f32x4 acc = {0.f, 0.f, 0.f, 0.f};
        #pragma unroll
        for (int kt = 0; kt < 4; ++kt) {
            half8 bh = *(const half8*)(Wf + (size_t)(((kt * NCT + ct) * 64 + l) * 8));
            half8 bl = *(const half8*)(Wf + (size_t)((((4 + kt) * NCT + ct) * 64 + l) * 8));
            acc = __builtin_amdgcn_mfma_f32_16x16x32_f16(Ahi[kt], bh, acc, 0, 0, 0);
            acc = __builtin_amdgcn_mfma_f32_16x16x32_f16(Alo[kt], bh, acc, 0, 0, 0);
            acc = __builtin_amdgcn_mfma_f32_16x16x32_f16(Ahi[kt], bl, acc, 0, 0, 0);
        }
        #pragma unroll
        for (int r = 0; r < 4; ++r) {
            int gr = row0 + cdr + r;
            if (gr < NN) {
                size_t oi = (size_t)gr * (NCT * 16) + ct * 16 + cdc;
                if constexpr (OUT16) ((h16*)out)[oi] = (h16)acc[r];
                else                 ((float*)out)[oi] = acc[r];
            }
        }
    }
}

template<int NCTA, int NCTB, bool A16, bool B16>
__global__ __launch_bounds__(256) void k_mfma(const h16* __restrict__ hhi,
        const h16* __restrict__ hlo, const h16* __restrict__ WfA,
        const h16* __restrict__ WfB, void* __restrict__ outA,
        void* __restrict__ outB) {
    const int tid = threadIdx.x;
    const int l   = tid & 63;
    const int wv  = tid >> 6;
    const int row0 = blockIdx.x * 64 + wv * 16;
    int ar = row0 + (l & 15); if (ar >= NN) ar = NN - 1;   // A: row = lane&15
    const size_t ab = (size_t)ar * F + (l >> 4) * 8;       //    k = kt*32+(lane>>4)*8+j
    half8 Ahi[4], Alo[4];
    #pragma unroll
    for (int kt = 0; kt < 4; ++kt) {
        Ahi[kt] = *(const half8*)(hhi + ab + kt * 32);
        Alo[kt] = *(const half8*)(hlo + ab + kt * 32);
    }
    mfma_cols<NCTA, A16>(Ahi, Alo, WfA, outA, row0, l);
    if constexpr (NCTB > 0) mfma_cols<NCTB, B16>(Ahi, Alo, WfB, outB, row0, l);
}

// ---------------- aggregation d=128, fp16 gather (256B rows, 4 rows/instr) ------
// MODE 0: mean  -> relu(s[v] + agg/max(deg,1) + b)     (s fp32, streamed)
// MODE 1: gcn   -> relu((agg + g[v])/(deg+1) + b)      (g fp16 self)
// Output: next layer's h as fp16 hi/lo split.
template<int MODE>
__global__ __launch_bounds__(256) void k_agg128(const h16* __restrict__ g,
        const float* __restrict__ s, const int* __restrict__ offs,
        const int* __restrict__ csr, const float* __restrict__ degf,
        const float* __restrict__ b, h16* __restrict__ hhi, h16* __restrict__ hlo) {
    const int wid  = (int)((blockIdx.x * 256 + threadIdx.x) >> 6);
    const int lane = threadIdx.x & 63;
    if (wid >= NN) return;
    const int q  = lane >> 4;       // row-group 0..3 (4 rows per instruction)
    const int li = lane & 15;       // half8 slot within the 256B row
    const int beg = offs[wid], end = offs[wid + 1];
    const half8* g8 = (const half8*)g;      // row stride = 16 half8
    float a0[8], a1[8];
    #pragma unroll
    for (int j = 0; j < 8; ++j) { a0[j] = 0.f; a1[j] = 0.f; }
    int e = beg;
    for (; e + 16 <= end; e += 16) {        // 16 rows in flight
        int u0 = csr[e + q];
        int u1 = csr[e + 4 + q];
        int u2 = csr[e + 8 + q];
        int u3 = csr[e + 12 + q];
        half8 v0 = g8[(size_t)u0 * 16 + li];
        half8 v1 = g8[(size_t)u1 * 16 + li];
        half8 v2 = g8[(size_t)u2 * 16 + li];
        half8 v3 = g8[(size_t)u3 * 16 + li];
        #pragma unroll
        for (int j = 0; j < 8; ++j) {
            a0[j] += (float)v0[j] + (float)v2[j];
            a1[j] += (float)v1[j] + (float)v3[j];
        }
    }
    for (; e + 4 <= end; e += 4) {
        half8 v = g8[(size_t)csr[e + q] * 16 + li];
        #pragma unroll
        for (int j = 0; j < 8; ++j) a0[j] += (float)v[j];
    }
    if (q < end - e) {                      // tail 0..3 rows
        half8 v = g8[(size_t)csr[e + q] * 16 + li];
        #pragma unroll
        for (int j = 0; j < 8; ++j) a1[j] += (float)v[j];
    }
    #pragma unroll
    for (int j = 0; j < 8; ++j) {
        a0[j] += a1[j];
        a0[j] += __shfl_xor(a0[j], 16, 64);
        a0[j] += __shfl_xor(a0[j], 32, 64);
    }
    if (q) return;
    const float dg = degf[wid];
    float bb[8];
    *(float4*)(bb)     = *(const float4*)(b + li * 8);
    *(float4*)(bb + 4) = *(const float4*)(b + li * 8 + 4);
    float r[8];
    if (MODE == 0) {
        float inv = 1.f / fmaxf(dg, 1.f);
        float sv[8];
        *(float4*)(sv)     = *(const float4*)(s + (size_t)wid * F + li * 8);
        *(float4*)(sv + 4) = *(const float4*)(s + (size_t)wid * F + li * 8 + 4);
        #pragma unroll
        for (int j = 0; j < 8; ++j) r[j] = fmaxf(sv[j] + a0[j] * inv + bb[j], 0.f);
    } else {
        float inv = 1.f / (dg + 1.f);
        half8 gv = g8[(size_t)wid * 16 + li];
        #pragma unroll
        for (int j = 0; j < 8; ++j)
            r[j] = fmaxf((a0[j] + (float)gv[j]) * inv + bb[j], 0.f);
    }
    half8 vhi, vlo;
    #pragma unroll
    for (int j = 0; j < 8; ++j) {
        h16 hi = (h16)r[j];
        vhi[j] = hi;
        vlo[j] = (h16)(r[j] - (float)hi);
    }
    *(half8*)(hhi + (size_t)wid * F + li * 8) = vhi;
    *(half8*)(hlo + (size_t)wid * F + li * 8) = vlo;
}

// ---------------- aggregation d=32 (mean, no relu, fp32 in/out, final) ----------
__global__ __launch_bounds__(256) void k_agg32(const float* __restrict__ g,
        const float* __restrict__ s, const int* __restrict__ offs,
        const int* __restrict__ csr, const float* __restrict__ degf,
        const float* __restrict__ b, float* __restrict__ out) {
    const int wid  = (int)((blockIdx.x * 256 + threadIdx.x) >> 6);
    const int lane = threadIdx.x & 63;
    if (wid >= NN) return;
    const int grp = lane >> 3;
    const int li  = lane & 7;
    const int beg = offs[wid], end = offs[wid + 1];
    const float4* g4 = (const float4*)g;
    float4 a0 = make_float4(0, 0, 0, 0), a1 = a0;
    int e = beg + grp;
    for (; e + 8 < end; e += 16) {
        int u0 = csr[e], u1 = csr[e + 8];
        float4 v0 = g4[(size_t)u0 * 8 + li];
        float4 v1 = g4[(size_t)u1 * 8 + li];
        a0.x += v0.x; a0.y += v0.y; a0.z += v0.z; a0.w += v0.w;
        a1.x += v1.x; a1.y += v1.y; a1.z += v1.z; a1.w += v1.w;
    }
    if (e < end) {
        float4 v = g4[(size_t)csr[e] * 8 + li];
        a0.x += v.x; a0.y += v.y; a0.z += v.z; a0.w += v.w;
    }
    a0.x += a1.x; a0.y += a1.y; a0.z += a1.z; a0.w += a1.w;
    #pragma unroll
    for (int d = 8; d < 64; d <<= 1) {
        a0.x += __shfl_xor(a0.x, d, 64);
        a0.y += __shfl_xor(a0.y, d, 64);
        a0.z += __shfl_xor(a0.z, d, 64);
        a0.w += __shfl_xor(a0.w, d, 64);
    }
    if (grp) return;
    const float inv = 1.f / fmaxf(degf[wid], 1.f);
    float4 bb = ((const float4*)b)[li];
    float4 sv = ((const float4*)s)[(size_t)wid * 8 + li];
    float4 r;
    r.x = sv.x + a0.x * inv + bb.x;
    r.y = sv.y + a0.y * inv + bb.y;
    r.z = sv.z + a0.z * inv + bb.z;
    r.w = sv.w + a0.w * inv + bb.w;
    ((float4*)out)[(size_t)wid * 8 + li] = r;
}

extern "C" void kernel_launch(void* const* d_in, const int* in_sizes, int n_in,
                              void* d_out, int out_size, void* d_ws, size_t ws_size,
                              hipStream_t stream) {
    const float* x       = (const float*)d_in[0];
    const int*   src     = (const int*)  d_in[1];
    const int*   dst     = (const int*)  d_in[2];
    const float* Wself0  = (const float*)d_in[3];
    const float* Wneigh0 = (const float*)d_in[4];
    const float* b0      = (const float*)d_in[5];
    const float* Wneigh1 = (const float*)d_in[6];
    const float* b1      = (const float*)d_in[7];
    const float* Wneigh2 = (const float*)d_in[8];
    const float* b2      = (const float*)d_in[9];
    const float* Wself3  = (const float*)d_in[10];
    const float* Wneigh3 = (const float*)d_in[11];
    const float* b3      = (const float*)d_in[12];
    float* out = (float*)d_out;

    char* ws = (char*)d_ws;
    size_t off = 0;
    auto alloc = [&](size_t bytes) -> void* {
        void* p = ws + off;
        off += (bytes + 255) & ~(size_t)255;
        return p;
    };
    int*   degi   = (int*)  alloc((size_t)NN * 4);
    float* degf   = (float*)alloc((size_t)NN * 4);
    int*   offs   = (int*)  alloc((size_t)(NN + 1) * 4);
    int*   cursor = (int*)  alloc((size_t)(NN + 1) * 4);
    int*   csr    = (int*)  alloc((size_t)NE * 4);
    int*   bsum   = (int*)  alloc((size_t)NB * 4);
    int*   bpre   = (int*)  alloc((size_t)NB * 4);
    h16*   hhi    = (h16*)  alloc((size_t)NN * F * 2);
    h16*   hlo    = (h16*)  alloc((size_t)NN * F * 2);
    h16*   gh     = (h16*)  alloc((size_t)NN * F * 2);   // fp16 gather operand
    float* bufg   = (float*)alloc((size_t)NN * F * 4);
    float* bufs   = (float*)alloc((size_t)NN * F * 4);
    h16*   WfS0   = (h16*)  alloc((size_t)128 * 128 * 2 * 2);
    h16*   WfN0   = (h16*)  alloc((size_t)128 * 128 * 2 * 2);
    h16*   WfN1   = (h16*)  alloc((size_t)128 * 128 * 2 * 2);
    h16*   WfN2   = (h16*)  alloc((size_t)128 * 128 * 2 * 2);
    h16*   WfS3   = (h16*)  alloc((size_t)128 * 32 * 2 * 2);
    h16*   WfN3   = (h16*)  alloc((size_t)128 * 32 * 2 * 2);

    hipMemsetAsync(degi, 0, (size_t)NN * 4, stream);

    const int egrid = (NE + 255) / 256;
    const int wgrid = (NN + 3) / 4;           // one wave per node
    const int mgrid = (NN + 63) / 64;         // 64 rows per block (4 waves x 16)

    k_wprep_all<<<288, 256, 0, stream>>>(Wself0, Wneigh0, Wneigh1, Wneigh2,
                                         Wself3, Wneigh3,
                                         WfS0, WfN0, WfN1, WfN2, WfS3, WfN3);

    k_deg     <<<egrid, 256, 0, stream>>>(dst, degi);
    k_bsum    <<<NB, 1024, 0, stream>>>(degi, degf, bsum);
    k_bscan   <<<1, 64, 0, stream>>>(bsum, bpre, offs);
    k_bscatter<<<NB, 1024, 0, stream>>>(degi, bpre, offs, cursor);
    k_fill    <<<egrid, 256, 0, stream>>>(src, dst, cursor, csr);
    k_l2norm  <<<wgrid, 256, 0, stream>>>(x, hhi, hlo);

    // layer 0 (mean): fused self(fp32)+neigh(fp16) GEMM, then aggregate
    k_mfma<8, 8, false, true><<<mgrid, 256, 0, stream>>>(hhi, hlo, WfS0, WfN0, bufs, gh);
    k_agg128<0><<<wgrid, 256, 0, stream>>>(gh, bufs, offs, csr, degf, b0, hhi, hlo);

    // layer 1 (gcn): fp16 g for gather + self
    k_mfma<8, 0, true, false><<<mgrid, 256, 0, stream>>>(hhi, hlo, WfN1, nullptr, gh, nullptr);
    k_agg128<1><<<wgrid, 256, 0, stream>>>(gh, nullptr, offs, csr, degf, b1, hhi, hlo);

    // layer 2 (gcn)
    k_mfma<8, 0, true, false><<<mgrid, 256, 0, stream>>>(hhi, hlo, WfN2, nullptr, gh, nullptr);
    k_agg128<1><<<wgrid, 256, 0, stream>>>(gh, nullptr, offs, csr, degf, b2, hhi, hlo);

    // layer 3 (mean, 128->32): fp32 both (gather already only 128B/row)
    k_mfma<2, 2, false, false><<<mgrid, 256, 0, stream>>>(hhi, hlo, WfS3, WfN3, bufs, bufg);
    k_agg32<<<wgrid, 256, 0, stream>>>(bufg, bufs, offs, csr, degf, b3, out);
}

// Round 6
// 324.990 us; speedup vs baseline: 1.9395x; 1.1990x over previous
//
#include <hip/hip_runtime.h>

#define NN 50000
#define NE 800000
#define F  128
#define FO 32

#define RSH  8                       // 256-node dst ranges
#define RSZ  256
#define NBKT 196                     // ceil(NN/256)
#define CAP  5120                    // per-bucket capacity (mean 4096 + 16 sigma)
#define PCHUNK 4096                  // edges per partition block
#define NPB  ((NE + PCHUNK - 1) / PCHUNK)   // 196

typedef _Float16 h16;
typedef h16   half8 __attribute__((ext_vector_type(8)));
typedef h16   h16x2 __attribute__((ext_vector_type(2)));
typedef float f32x4 __attribute__((ext_vector_type(4)));

// ---------------- phase 1: partition edges into dst-range buckets ----------------
__global__ __launch_bounds__(256) void k_part(const int* __restrict__ src,
        const int* __restrict__ dst, int* __restrict__ bcur, int* __restrict__ barea) {
    __shared__ int cnt[NBKT];
    __shared__ int base[NBKT];
    const int tid = threadIdx.x;
    const int e0  = blockIdx.x * PCHUNK;
    for (int i = tid; i < NBKT; i += 256) cnt[i] = 0;
    __syncthreads();
    #pragma unroll
    for (int k = 0; k < PCHUNK / 256; ++k) {
        int e = e0 + k * 256 + tid;
        if (e < NE) atomicAdd(&cnt[dst[e] >> RSH], 1);
    }
    __syncthreads();
    for (int i = tid; i < NBKT; i += 256)
        base[i] = atomicAdd(&bcur[i], cnt[i]);       // reserve block-private range
    __syncthreads();
    for (int i = tid; i < NBKT; i += 256) cnt[i] = base[i];   // reuse as cursor
    __syncthreads();
    #pragma unroll
    for (int k = 0; k < PCHUNK / 256; ++k) {
        int e = e0 + k * 256 + tid;
        if (e < NE) {
            int d = dst[e], s = src[e];
            int b = d >> RSH;
            int p = atomicAdd(&cnt[b], 1);
            barea[b * CAP + p] = ((d & (RSZ - 1)) << 16) | s;   // src < 2^16
        }
    }
}

// ---------------- phase 2a: scan 196 bucket sizes ----------------
__global__ __launch_bounds__(256) void k_bscan(const int* __restrict__ bcur,
        int* __restrict__ bpre, int* __restrict__ offs) {
    __shared__ int ws[4];
    const int tid = threadIdx.x, lane = tid & 63, wv = tid >> 6;
    int v = (tid < NBKT) ? bcur[tid] : 0;
    int incl = v;
    #pragma unroll
    for (int d = 1; d < 64; d <<= 1) {
        int t = __shfl_up(incl, d, 64);
        if (lane >= d) incl += t;
    }
    if (lane == 63) ws[wv] = incl;
    __syncthreads();
    if (tid == 0) {
        int run = 0;
        #pragma unroll
        for (int w = 0; w < 4; ++w) { int t = ws[w]; ws[w] = run; run += t; }
    }
    __syncthreads();
    int excl = ws[wv] + incl - v;
    if (tid < NBKT) bpre[tid] = excl;
    if (tid == NBKT - 1) offs[NN] = excl + v;   // == NE
}

// ---------------- phase 2b: per-bucket hist + scan + CSR fill ----------------
// csr writes are random ONLY within a ~16KB window -> single-XCD L2 resident,
// lines fill completely before eviction (kills the 64B write amplification).
__global__ __launch_bounds__(256) void k_bfill(const int* __restrict__ barea,
        const int* __restrict__ bcur, const int* __restrict__ bpre,
        int* __restrict__ offs, float* __restrict__ degf, int* __restrict__ csr) {
    __shared__ int hist_cur[RSZ];
    __shared__ int ws[4];
    const int r = blockIdx.x, tid = threadIdx.x;
    const int nb    = bcur[r];
    const int gbase = bpre[r];
    const int node  = (r << RSH) + tid;
    hist_cur[tid] = 0;
    __syncthreads();
    const int* area = barea + r * CAP;
    for (int i = tid; i < nb; i += 256) atomicAdd(&hist_cur[area[i] >> 16], 1);
    __syncthreads();
    const int v = hist_cur[tid];
    const int lane = tid & 63, wv = tid >> 6;
    int incl = v;
    #pragma unroll
    for (int d = 1; d < 64; d <<= 1) {
        int t = __shfl_up(incl, d, 64);
        if (lane >= d) incl += t;
    }
    if (lane == 63) ws[wv] = incl;
    __syncthreads();
    if (tid == 0) {
        int run = 0;
        #pragma unroll
        for (int w = 0; w < 4; ++w) { int t = ws[w]; ws[w] = run; run += t; }
    }
    __syncthreads();
    const int ex = ws[wv] + incl - v;
    if (node < NN) {
        offs[node] = gbase + ex;
        degf[node] = (float)v;
    }
    __syncthreads();
    hist_cur[tid] = gbase + ex;     // becomes the scatter cursor
    __syncthreads();
    for (int i = tid; i < nb; i += 256) {
        int pk = area[i];
        int p = atomicAdd(&hist_cur[pk >> 16], 1);
        csr[p] = pk & 0xFFFF;
    }
}

// ---------------- weight prep: fp32 W[K=128][NC] -> fragment-ordered fp16 hi/lo --
__device__ __forceinline__ void wprep_one(const float* __restrict__ W,
        h16* __restrict__ Wf, int idx, int NC, int NCT) {
    if (idx >= 128 * NC) return;
    int k = idx / NC, n = idx - k * NC;
    int kt = k >> 5, g = (k & 31) >> 3, j = k & 7;
    int ct = n >> 4;
    int lane = g * 16 + (n & 15);
    float w = W[idx];
    h16 hi = (h16)w;
    h16 lo = (h16)(w - (float)hi);
    int base = ((kt * NCT + ct) * 64 + lane) * 8 + j;
    Wf[base] = hi;
    Wf[base + NCT * 2048] = lo;   // part stride = 4*NCT*64*8
}

__global__ __launch_bounds__(256) void k_wprep_all(
        const float* __restrict__ S0, const float* __restrict__ N0,
        const float* __restrict__ N1, const float* __restrict__ N2,
        const float* __restrict__ S3, const float* __restrict__ N3,
        h16* fS0, h16* fN0, h16* fN1, h16* fN2, h16* fS3, h16* fN3) {
    int bb = blockIdx.x, tid = threadIdx.x;
    if (bb < 256) {
        const float* W = bb < 64 ? S0 : bb < 128 ? N0 : bb < 192 ? N1 : N2;
        h16*        Wf = bb < 64 ? fS0 : bb < 128 ? fN0 : bb < 192 ? fN1 : fN2;
        wprep_one(W, Wf, (bb & 63) * 256 + tid, 128, 8);
    } else {
        int b2 = bb - 256;
        const float* W = b2 < 16 ? S3 : N3;
        h16*        Wf = b2 < 16 ? fS3 : fN3;
        wprep_one(W, Wf, (b2 & 15) * 256 + tid, 32, 2);
    }
}

// ---------------- row L2 normalize -> split fp16 hi/lo ----------------
__global__ __launch_bounds__(256) void k_l2norm(const float* __restrict__ x,
        h16* __restrict__ hhi, h16* __restrict__ hlo) {
    const int wid  = (int)((blockIdx.x * 256 + threadIdx.x) >> 6);
    const int lane = threadIdx.x & 63;
    if (wid >= NN) return;
    const float2* xr = (const float2*)(x + (size_t)wid * F);
    float2 v = xr[lane];
    float ss = v.x * v.x + v.y * v.y;
    #pragma unroll
    for (int d = 1; d < 64; d <<= 1) ss += __shfl_xor(ss, d, 64);
    float inv = 1.0f / fmaxf(sqrtf(ss), 1e-12f);
    float ox = v.x * inv, oy = v.y * inv;
    h16 hx = (h16)ox, hy = (h16)oy;
    h16x2 vhi = {hx, hy};
    h16x2 vlo = {(h16)(ox - (float)hx), (h16)(oy - (float)hy)};
    *(h16x2*)(hhi + (size_t)wid * F + lane * 2) = vhi;
    *(h16x2*)(hlo + (size_t)wid * F + lane * 2) = vlo;
}

// ---------------- fp16-split MFMA GEMM: out = h @ W ----------------
template<int NCT, bool OUT16>
__device__ __forceinline__ void mfma_cols(const half8* Ahi, const half8* Alo,
        const h16* __restrict__ Wf, void* __restrict__ out, int row0, int l) {
    const int cdc = l & 15;          // C/D: col = lane&15
    const int cdr = (l >> 4) * 4;    //      row = (lane>>4)*4 + reg   [m89]
    #pragma unroll
    for (int ct = 0; ct < NCT; ++ct) {
        f32x4 acc = {0.f, 0.f, 0.f, 0.f};
        #pragma unroll
        for (int kt = 0; kt < 4; ++kt) {
            half8 bh = *(const half8*)(Wf + (size_t)(((kt * NCT + ct) * 64 + l) * 8));
            half8 bl = *(const half8*)(Wf + (size_t)((((4 + kt) * NCT + ct) * 64 + l) * 8));
            acc = __builtin_amdgcn_mfma_f32_16x16x32_f16(Ahi[kt], bh, acc, 0, 0, 0);
            acc = __builtin_amdgcn_mfma_f32_16x16x32_f16(Alo[kt], bh, acc, 0, 0, 0);
            acc = __builtin_amdgcn_mfma_f32_16x16x32_f16(Ahi[kt], bl, acc, 0, 0, 0);
        }
        #pragma unroll
        for (int r = 0; r < 4; ++r) {
            int gr = row0 + cdr + r;
            if (gr < NN) {
                size_t oi = (size_t)gr * (NCT * 16) + ct * 16 + cdc;
                if constexpr (OUT16) ((h16*)out)[oi] = (h16)acc[r];
                else                 ((float*)out)[oi] = acc[r];
            }
        }
    }
}

template<int NCTA, int NCTB, bool A16, bool B16>
__global__ __launch_bounds__(256) void k_mfma(const h16* __restrict__ hhi,
        const h16* __restrict__ hlo, const h16* __restrict__ WfA,
        const h16* __restrict__ WfB, void* __restrict__ outA,
        void* __restrict__ outB) {
    const int tid = threadIdx.x;
    const int l   = tid & 63;
    const int wv  = tid >> 6;
    const int row0 = blockIdx.x * 64 + wv * 16;
    int ar = row0 + (l & 15); if (ar >= NN) ar = NN - 1;   // A: row = lane&15
    const size_t ab = (size_t)ar * F + (l >> 4) * 8;       //    k = kt*32+(lane>>4)*8+j
    half8 Ahi[4], Alo[4];
    #pragma unroll
    for (int kt = 0; kt < 4; ++kt) {
        Ahi[kt] = *(const half8*)(hhi + ab + kt * 32);
        Alo[kt] = *(const half8*)(hlo + ab + kt * 32);
    }
    mfma_cols<NCTA, A16>(Ahi, Alo, WfA, outA, row0, l);
    if constexpr (NCTB > 0) mfma_cols<NCTB, B16>(Ahi, Alo, WfB, outB, row0, l);
}

// ---------------- aggregation d=128, fp16 gather (256B rows, 4 rows/instr) ------
template<int MODE>
__global__ __launch_bounds__(256) void k_agg128(const h16* __restrict__ g,
        const float* __restrict__ s, const int* __restrict__ offs,
        const int* __restrict__ csr, const float* __restrict__ degf,
        const float* __restrict__ b, h16* __restrict__ hhi, h16* __restrict__ hlo) {
    const int wid  = (int)((blockIdx.x * 256 + threadIdx.x) >> 6);
    const int lane = threadIdx.x & 63;
    if (wid >= NN) return;
    const int q  = lane >> 4;       // row-group 0..3 (4 rows per instruction)
    const int li = lane & 15;       // half8 slot within the 256B row
    const int beg = offs[wid], end = offs[wid + 1];
    const half8* g8 = (const half8*)g;      // row stride = 16 half8
    float a0[8], a1[8];
    #pragma unroll
    for (int j = 0; j < 8; ++j) { a0[j] = 0.f; a1[j] = 0.f; }
    int e = beg;
    for (; e + 16 <= end; e += 16) {        // 16 rows in flight
        int u0 = csr[e + q];
        int u1 = csr[e + 4 + q];
        int u2 = csr[e + 8 + q];
        int u3 = csr[e + 12 + q];
        half8 v0 = g8[(size_t)u0 * 16 + li];
        half8 v1 = g8[(size_t)u1 * 16 + li];
        half8 v2 = g8[(size_t)u2 * 16 + li];
        half8 v3 = g8[(size_t)u3 * 16 + li];
        #pragma unroll
        for (int j = 0; j < 8; ++j) {
            a0[j] += (float)v0[j] + (float)v2[j];
            a1[j] += (float)v1[j] + (float)v3[j];
        }
    }
    for (; e + 4 <= end; e += 4) {
        half8 v = g8[(size_t)csr[e + q] * 16 + li];
        #pragma unroll
        for (int j = 0; j < 8; ++j) a0[j] += (float)v[j];
    }
    if (q < end - e) {                      // tail 0..3 rows
        half8 v = g8[(size_t)csr[e + q] * 16 + li];
        #pragma unroll
        for (int j = 0; j < 8; ++j) a1[j] += (float)v[j];
    }
    #pragma unroll
    for (int j = 0; j < 8; ++j) {
        a0[j] += a1[j];
        a0[j] += __shfl_xor(a0[j], 16, 64);
        a0[j] += __shfl_xor(a0[j], 32, 64);
    }
    if (q) return;
    const float dg = degf[wid];
    float bb[8];
    *(float4*)(bb)     = *(const float4*)(b + li * 8);
    *(float4*)(bb + 4) = *(const float4*)(b + li * 8 + 4);
    float r[8];
    if (MODE == 0) {
        float inv = 1.f / fmaxf(dg, 1.f);
        float sv[8];
        *(float4*)(sv)     = *(const float4*)(s + (size_t)wid * F + li * 8);
        *(float4*)(sv + 4) = *(const float4*)(s + (size_t)wid * F + li * 8 + 4);
        #pragma unroll
        for (int j = 0; j < 8; ++j) r[j] = fmaxf(sv[j] + a0[j] * inv + bb[j], 0.f);
    } else {
        float inv = 1.f / (dg + 1.f);
        half8 gv = g8[(size_t)wid * 16 + li];
        #pragma unroll
        for (int j = 0; j < 8; ++j)
            r[j] = fmaxf((a0[j] + (float)gv[j]) * inv + bb[j], 0.f);
    }
    half8 vhi, vlo;
    #pragma unroll
    for (int j = 0; j < 8; ++j) {
        h16 hi = (h16)r[j];
        vhi[j] = hi;
        vlo[j] = (h16)(r[j] - (float)hi);
    }
    *(half8*)(hhi + (size_t)wid * F + li * 8) = vhi;
    *(half8*)(hlo + (size_t)wid * F + li * 8) = vlo;
}

// ---------------- aggregation d=32 (mean, no relu, fp32 in/out, final) ----------
__global__ __launch_bounds__(256) void k_agg32(const float* __restrict__ g,
        const float* __restrict__ s, const int* __restrict__ offs,
        const int* __restrict__ csr, const float* __restrict__ degf,
        const float* __restrict__ b, float* __restrict__ out) {
    const int wid  = (int)((blockIdx.x * 256 + threadIdx.x) >> 6);
    const int lane = threadIdx.x & 63;
    if (wid >= NN) return;
    const int grp = lane >> 3;
    const int li  = lane & 7;
    const int beg = offs[wid], end = offs[wid + 1];
    const float4* g4 = (const float4*)g;
    float4 a0 = make_float4(0, 0, 0, 0), a1 = a0;
    int e = beg + grp;
    for (; e + 8 < end; e += 16) {
        int u0 = csr[e], u1 = csr[e + 8];
        float4 v0 = g4[(size_t)u0 * 8 + li];
        float4 v1 = g4[(size_t)u1 * 8 + li];
        a0.x += v0.x; a0.y += v0.y; a0.z += v0.z; a0.w += v0.w;
        a1.x += v1.x; a1.y += v1.y; a1.z += v1.z; a1.w += v1.w;
    }
    if (e < end) {
        float4 v = g4[(size_t)csr[e] * 8 + li];
        a0.x += v.x; a0.y += v.y; a0.z += v.z; a0.w += v.w;
    }
    a0.x += a1.x; a0.y += a1.y; a0.z += a1.z; a0.w += a1.w;
    #pragma unroll
    for (int d = 8; d < 64; d <<= 1) {
        a0.x += __shfl_xor(a0.x, d, 64);
        a0.y += __shfl_xor(a0.y, d, 64);
        a0.z += __shfl_xor(a0.z, d, 64);
        a0.w += __shfl_xor(a0.w, d, 64);
    }
    if (grp) return;
    const float inv = 1.f / fmaxf(degf[wid], 1.f);
    float4 bb = ((const float4*)b)[li];
    float4 sv = ((const float4*)s)[(size_t)wid * 8 + li];
    float4 r;
    r.x = sv.x + a0.x * inv + bb.x;
    r.y = sv.y + a0.y * inv + bb.y;
    r.z = sv.z + a0.z * inv + bb.z;
    r.w = sv.w + a0.w * inv + bb.w;
    ((float4*)out)[(size_t)wid * 8 + li] = r;
}

extern "C" void kernel_launch(void* const* d_in, const int* in_sizes, int n_in,
                              void* d_out, int out_size, void* d_ws, size_t ws_size,
                              hipStream_t stream) {
    const float* x       = (const float*)d_in[0];
    const int*   src     = (const int*)  d_in[1];
    const int*   dst     = (const int*)  d_in[2];
    const float* Wself0  = (const float*)d_in[3];
    const float* Wneigh0 = (const float*)d_in[4];
    const float* b0      = (const float*)d_in[5];
    const float* Wneigh1 = (const float*)d_in[6];
    const float* b1      = (const float*)d_in[7];
    const float* Wneigh2 = (const float*)d_in[8];
    const float* b2      = (const float*)d_in[9];
    const float* Wself3  = (const float*)d_in[10];
    const float* Wneigh3 = (const float*)d_in[11];
    const float* b3      = (const float*)d_in[12];
    float* out = (float*)d_out;

    char* ws = (char*)d_ws;
    size_t off = 0;
    auto alloc = [&](size_t bytes) -> void* {
        void* p = ws + off;
        off += (bytes + 255) & ~(size_t)255;
        return p;
    };
    float* degf   = (float*)alloc((size_t)NN * 4);
    int*   offs   = (int*)  alloc((size_t)(NN + 1) * 4);
    int*   csr    = (int*)  alloc((size_t)NE * 4);
    int*   bcur   = (int*)  alloc((size_t)NBKT * 4);
    int*   bpre   = (int*)  alloc((size_t)NBKT * 4);
    int*   barea  = (int*)  alloc((size_t)NBKT * CAP * 4);
    h16*   hhi    = (h16*)  alloc((size_t)NN * F * 2);
    h16*   hlo    = (h16*)  alloc((size_t)NN * F * 2);
    h16*   gh     = (h16*)  alloc((size_t)NN * F * 2);   // fp16 gather operand
    float* bufg   = (float*)alloc((size_t)NN * F * 4);
    float* bufs   = (float*)alloc((size_t)NN * F * 4);
    h16*   WfS0   = (h16*)  alloc((size_t)128 * 128 * 2 * 2);
    h16*   WfN0   = (h16*)  alloc((size_t)128 * 128 * 2 * 2);
    h16*   WfN1   = (h16*)  alloc((size_t)128 * 128 * 2 * 2);
    h16*   WfN2   = (h16*)  alloc((size_t)128 * 128 * 2 * 2);
    h16*   WfS3   = (h16*)  alloc((size_t)128 * 32 * 2 * 2);
    h16*   WfN3   = (h16*)  alloc((size_t)128 * 32 * 2 * 2);

    hipMemsetAsync(bcur, 0, (size_t)NBKT * 4, stream);

    const int wgrid = (NN + 3) / 4;           // one wave per node
    const int mgrid = (NN + 63) / 64;         // 64 rows per block (4 waves x 16)

    k_wprep_all<<<288, 256, 0, stream>>>(Wself0, Wneigh0, Wneigh1, Wneigh2,
                                         Wself3, Wneigh3,
                                         WfS0, WfN0, WfN1, WfN2, WfS3, WfN3);

    k_part  <<<NPB, 256, 0, stream>>>(src, dst, bcur, barea);
    k_bscan <<<1, 256, 0, stream>>>(bcur, bpre, offs);
    k_bfill <<<NBKT, 256, 0, stream>>>(barea, bcur, bpre, offs, degf, csr);
    k_l2norm<<<wgrid, 256, 0, stream>>>(x, hhi, hlo);

    // layer 0 (mean): fused self(fp32)+neigh(fp16) GEMM, then aggregate
    k_mfma<8, 8, false, true><<<mgrid, 256, 0, stream>>>(hhi, hlo, WfS0, WfN0, bufs, gh);
    k_agg128<0><<<wgrid, 256, 0, stream>>>(gh, bufs, offs, csr, degf, b0, hhi, hlo);

    // layer 1 (gcn)
    k_mfma<8, 0, true, false><<<mgrid, 256, 0, stream>>>(hhi, hlo, WfN1, nullptr, gh, nullptr);
    k_agg128<1><<<wgrid, 256, 0, stream>>>(gh, nullptr, offs, csr, degf, b1, hhi, hlo);

    // layer 2 (gcn)
    k_mfma<8, 0, true, false><<<mgrid, 256, 0, stream>>>(hhi, hlo, WfN2, nullptr, gh, nullptr);
    k_agg128<1><<<wgrid, 256, 0, stream>>>(gh, nullptr, offs, csr, degf, b2, hhi, hlo);

    // layer 3 (mean, 128->32): fp32 both (gather already only 128B/row)
    k_mfma<2, 2, false, false><<<mgrid, 256, 0, stream>>>(hhi, hlo, WfS3, WfN3, bufs, bufg);
    k_agg32<<<wgrid, 256, 0, stream>>>(bufg, bufs, offs, csr, degf, b3, out);
}

// Round 7
// 313.719 us; speedup vs baseline: 2.0091x; 1.0359x over previous
//
#include <hip/hip_runtime.h>

#define NN 50000
#define NE 800000
#define F  128
#define FO 32

#define RSH  8                       // 256-node dst ranges
#define RSZ  256
#define NBKT 196                     // ceil(NN/256)
#define CAP  5120                    // per-bucket capacity (mean 4082 + 16 sigma)
#define PCHUNK 4096                  // edges per partition block
#define NPB  ((NE + PCHUNK - 1) / PCHUNK)   // 196
#define LGRID ((NN + 3) / 4)         // l2norm/agg blocks (4 waves of 1 node each)

typedef _Float16 h16;
typedef h16   half8 __attribute__((ext_vector_type(8)));
typedef h16   h16x4 __attribute__((ext_vector_type(4)));
typedef h16   h16x2 __attribute__((ext_vector_type(2)));
typedef float f32x4 __attribute__((ext_vector_type(4)));

// ---------------- weight prep: fp32 W[K=128][NC] -> fragment-ordered fp16 hi/lo --
// B-frag layout for mfma_f32_16x16x32_f16: col n = ct*16 + (lane&15),
// k = kt*32 + (lane>>4)*8 + j. Wf idx: (((part*4+kt)*NCT + ct)*64 + lane)*8 + j.
__device__ __forceinline__ void wprep_one(const float* __restrict__ W,
        h16* __restrict__ Wf, int idx, int NC, int NCT) {
    if (idx >= 128 * NC) return;
    int k = idx / NC, n = idx - k * NC;
    int kt = k >> 5, g = (k & 31) >> 3, j = k & 7;
    int ct = n >> 4;
    int lane = g * 16 + (n & 15);
    float w = W[idx];
    h16 hi = (h16)w;
    h16 lo = (h16)(w - (float)hi);
    int base = ((kt * NCT + ct) * 64 + lane) * 8 + j;
    Wf[base] = hi;
    Wf[base + NCT * 2048] = lo;   // part stride = 4*NCT*64*8
}

// blocks [0,288): weight prep; block 288: zero bucket cursors
__global__ __launch_bounds__(256) void k_pre0(
        const float* __restrict__ S0, const float* __restrict__ N0,
        const float* __restrict__ N1, const float* __restrict__ N2,
        const float* __restrict__ S3, const float* __restrict__ N3,
        h16* fS0, h16* fN0, h16* fN1, h16* fN2, h16* fS3, h16* fN3,
        int* __restrict__ bcur) {
    int bb = blockIdx.x, tid = threadIdx.x;
    if (bb < 256) {
        const float* W = bb < 64 ? S0 : bb < 128 ? N0 : bb < 192 ? N1 : N2;
        h16*        Wf = bb < 64 ? fS0 : bb < 128 ? fN0 : bb < 192 ? fN1 : fN2;
        wprep_one(W, Wf, (bb & 63) * 256 + tid, 128, 8);
    } else if (bb < 288) {
        int b2 = bb - 256;
        const float* W = b2 < 16 ? S3 : N3;
        h16*        Wf = b2 < 16 ? fS3 : fN3;
        wprep_one(W, Wf, (b2 & 15) * 256 + tid, 32, 2);
    } else {
        if (tid < NBKT) bcur[tid] = 0;
    }
}

// ---------------- fused: edge partition (blocks [0,NPB)) + l2norm (rest) --------
__global__ __launch_bounds__(256) void k_pre1(const int* __restrict__ src,
        const int* __restrict__ dst, int* __restrict__ bcur, int* __restrict__ barea,
        const float* __restrict__ x, h16* __restrict__ hhi, h16* __restrict__ hlo) {
    __shared__ int cnt[NBKT];
    __shared__ int base[NBKT];
    const int tid = threadIdx.x;
    if ((int)blockIdx.x < NPB) {
        const int e0 = blockIdx.x * PCHUNK;
        for (int i = tid; i < NBKT; i += 256) cnt[i] = 0;
        __syncthreads();
        #pragma unroll
        for (int k = 0; k < PCHUNK / 256; ++k) {
            int e = e0 + k * 256 + tid;
            if (e < NE) atomicAdd(&cnt[dst[e] >> RSH], 1);
        }
        __syncthreads();
        for (int i = tid; i < NBKT; i += 256)
            base[i] = atomicAdd(&bcur[i], cnt[i]);       // reserve private range
        __syncthreads();
        for (int i = tid; i < NBKT; i += 256) cnt[i] = base[i];   // reuse as cursor
        __syncthreads();
        #pragma unroll
        for (int k = 0; k < PCHUNK / 256; ++k) {
            int e = e0 + k * 256 + tid;
            if (e < NE) {
                int d = dst[e], s = src[e];
                int b = d >> RSH;
                int p = atomicAdd(&cnt[b], 1);
                barea[b * CAP + p] = ((d & (RSZ - 1)) << 16) | s;   // src < 2^16
            }
        }
    } else {
        const int bb   = blockIdx.x - NPB;
        const int wid  = bb * 4 + (tid >> 6);
        const int lane = tid & 63;
        if (wid >= NN) return;
        const float2* xr = (const float2*)(x + (size_t)wid * F);
        float2 v = xr[lane];
        float ss = v.x * v.x + v.y * v.y;
        #pragma unroll
        for (int d = 1; d < 64; d <<= 1) ss += __shfl_xor(ss, d, 64);
        float inv = 1.0f / fmaxf(sqrtf(ss), 1e-12f);
        float ox = v.x * inv, oy = v.y * inv;
        h16 hx = (h16)ox, hy = (h16)oy;
        h16x2 vhi = {hx, hy};
        h16x2 vlo = {(h16)(ox - (float)hx), (h16)(oy - (float)hy)};
        *(h16x2*)(hhi + (size_t)wid * F + lane * 2) = vhi;
        *(h16x2*)(hlo + (size_t)wid * F + lane * 2) = vlo;
    }
}

// ---------------- per-bucket: global scan (redundant per block) + hist + fill ----
// csr writes random only within a ~16KB window -> L2-resident, no write amplify.
__global__ __launch_bounds__(256) void k_bfill(const int* __restrict__ barea,
        const int* __restrict__ bcur, int* __restrict__ offs,
        float* __restrict__ degf, int* __restrict__ csr) {
    __shared__ int pre[NBKT];
    __shared__ int hist_cur[RSZ];
    __shared__ int ws[4];
    const int r = blockIdx.x, tid = threadIdx.x;
    const int lane = tid & 63, wv = tid >> 6;
    // scan the 196 bucket sizes (every block does it; 196 ints, L2-hot)
    int bv = (tid < NBKT) ? bcur[tid] : 0;
    int bi = bv;
    #pragma unroll
    for (int d = 1; d < 64; d <<= 1) {
        int t = __shfl_up(bi, d, 64);
        if (lane >= d) bi += t;
    }
    if (lane == 63) ws[wv] = bi;
    __syncthreads();
    if (tid == 0) {
        int run = 0;
        #pragma unroll
        for (int w = 0; w < 4; ++w) { int t = ws[w]; ws[w] = run; run += t; }
    }
    __syncthreads();
    if (tid < NBKT) pre[tid] = ws[wv] + bi - bv;
    if (r == 0 && tid == NBKT - 1) offs[NN] = ws[wv] + bi;   // == NE
    __syncthreads();
    const int nb    = bcur[r];
    const int gbase = pre[r];
    const int node  = (r << RSH) + tid;
    hist_cur[tid] = 0;
    __syncthreads();
    const int* area = barea + r * CAP;
    for (int i = tid; i < nb; i += 256) atomicAdd(&hist_cur[area[i] >> 16], 1);
    __syncthreads();
    const int v = hist_cur[tid];
    int incl = v;
    #pragma unroll
    for (int d = 1; d < 64; d <<= 1) {
        int t = __shfl_up(incl, d, 64);
        if (lane >= d) incl += t;
    }
    __syncthreads();            // ws reuse
    if (lane == 63) ws[wv] = incl;
    __syncthreads();
    if (tid == 0) {
        int run = 0;
        #pragma unroll
        for (int w = 0; w < 4; ++w) { int t = ws[w]; ws[w] = run; run += t; }
    }
    __syncthreads();
    const int ex = ws[wv] + incl - v;
    if (node < NN) {
        offs[node] = gbase + ex;
        degf[node] = (float)v;
    }
    __syncthreads();
    hist_cur[tid] = gbase + ex;     // becomes the scatter cursor
    __syncthreads();
    for (int i = tid; i < nb; i += 256) {
        int pk = area[i];
        int p = atomicAdd(&hist_cur[pk >> 16], 1);
        csr[p] = pk & 0xFFFF;
    }
}

// ---------------- fp16-split MFMA GEMM: out = h @ W (Ootomo 3-term) ----------------
template<int NCT, bool OUT16>
__device__ __forceinline__ void mfma_cols(const half8* Ahi, const half8* Alo,
        const h16* __restrict__ Wf, void* __restrict__ out, int row0, int l) {
    const int cdc = l & 15;          // C/D: col = lane&15
    const int cdr = (l >> 4) * 4;    //      row = (lane>>4)*4 + reg   [m89]
    #pragma unroll
    for (int ct = 0; ct < NCT; ++ct) {
        f32x4 acc = {0.f, 0.f, 0.f, 0.f};
        #pragma unroll
        for (int kt = 0; kt < 4; ++kt) {
            half8 bh = *(const half8*)(Wf + (size_t)(((kt * NCT + ct) * 64 + l) * 8));
            half8 bl = *(const half8*)(Wf + (size_t)((((4 + kt) * NCT + ct) * 64 + l) * 8));
            acc = __builtin_amdgcn_mfma_f32_16x16x32_f16(Ahi[kt], bh, acc, 0, 0, 0);
            acc = __builtin_amdgcn_mfma_f32_16x16x32_f16(Alo[kt], bh, acc, 0, 0, 0);
            acc = __builtin_amdgcn_mfma_f32_16x16x32_f16(Ahi[kt], bl, acc, 0, 0, 0);
        }
        #pragma unroll
        for (int r = 0; r < 4; ++r) {
            int gr = row0 + cdr + r;
            if (gr < NN) {
                size_t oi = (size_t)gr * (NCT * 16) + ct * 16 + cdc;
                if constexpr (OUT16) ((h16*)out)[oi] = (h16)acc[r];
                else                 ((float*)out)[oi] = acc[r];
            }
        }
    }
}

template<int NCTA, int NCTB, bool A16, bool B16>
__global__ __launch_bounds__(256) void k_mfma(const h16* __restrict__ hhi,
        const h16* __restrict__ hlo, const h16* __restrict__ WfA,
        const h16* __restrict__ WfB, void* __restrict__ outA,
        void* __restrict__ outB) {
    const int tid = threadIdx.x;
    const int l   = tid & 63;
    const int wv  = tid >> 6;
    const int row0 = blockIdx.x * 64 + wv * 16;
    int ar = row0 + (l & 15); if (ar >= NN) ar = NN - 1;   // A: row = lane&15
    const size_t ab = (size_t)ar * F + (l >> 4) * 8;       //    k = kt*32+(lane>>4)*8+j
    half8 Ahi[4], Alo[4];
    #pragma unroll
    for (int kt = 0; kt < 4; ++kt) {
        Ahi[kt] = *(const half8*)(hhi + ab + kt * 32);
        Alo[kt] = *(const half8*)(hlo + ab + kt * 32);
    }
    mfma_cols<NCTA, A16>(Ahi, Alo, WfA, outA, row0, l);
    if constexpr (NCTB > 0) mfma_cols<NCTB, B16>(Ahi, Alo, WfB, outB, row0, l);
}

// ---------------- aggregation d=128, fp16 gather (256B rows, 4 rows/instr) ------
// MODE 0: mean  -> relu(s[v] + agg/max(deg,1) + b)     (s fp16)
// MODE 1: gcn   -> relu((agg + g[v])/(deg+1) + b)      (g fp16 self)
template<int MODE>
__global__ __launch_bounds__(256) void k_agg128(const h16* __restrict__ g,
        const h16* __restrict__ s, const int* __restrict__ offs,
        const int* __restrict__ csr, const float* __restrict__ degf,
        const float* __restrict__ b, h16* __restrict__ hhi, h16* __restrict__ hlo) {
    const int wid  = (int)((blockIdx.x * 256 + threadIdx.x) >> 6);
    const int lane = threadIdx.x & 63;
    if (wid >= NN) return;
    const int q  = lane >> 4;       // row-group 0..3 (4 rows per instruction)
    const int li = lane & 15;       // half8 slot within the 256B row
    const int beg = offs[wid], end = offs[wid + 1];
    const half8* g8 = (const half8*)g;      // row stride = 16 half8
    float a0[8], a1[8];
    #pragma unroll
    for (int j = 0; j < 8; ++j) { a0[j] = 0.f; a1[j] = 0.f; }
    int e = beg;
    for (; e + 16 <= end; e += 16) {        // 16 rows in flight
        int u0 = csr[e + q];
        int u1 = csr[e + 4 + q];
        int u2 = csr[e + 8 + q];
        int u3 = csr[e + 12 + q];
        half8 v0 = g8[(size_t)u0 * 16 + li];
        half8 v1 = g8[(size_t)u1 * 16 + li];
        half8 v2 = g8[(size_t)u2 * 16 + li];
        half8 v3 = g8[(size_t)u3 * 16 + li];
        #pragma unroll
        for (int j = 0; j < 8; ++j) {
            a0[j] += (float)v0[j] + (float)v2[j];
            a1[j] += (float)v1[j] + (float)v3[j];
        }
    }
    for (; e + 4 <= end; e += 4) {
        half8 v = g8[(size_t)csr[e + q] * 16 + li];
        #pragma unroll
        for (int j = 0; j < 8; ++j) a0[j] += (float)v[j];
    }
    if (q < end - e) {                      // tail 0..3 rows
        half8 v = g8[(size_t)csr[e + q] * 16 + li];
        #pragma unroll
        for (int j = 0; j < 8; ++j) a1[j] += (float)v[j];
    }
    #pragma unroll
    for (int j = 0; j < 8; ++j) {
        a0[j] += a1[j];
        a0[j] += __shfl_xor(a0[j], 16, 64);
        a0[j] += __shfl_xor(a0[j], 32, 64);
    }
    if (q) return;
    const float dg = degf[wid];
    float bb[8];
    *(float4*)(bb)     = *(const float4*)(b + li * 8);
    *(float4*)(bb + 4) = *(const float4*)(b + li * 8 + 4);
    float r[8];
    if (MODE == 0) {
        float inv = 1.f / fmaxf(dg, 1.f);
        half8 sv = ((const half8*)s)[(size_t)wid * 16 + li];
        #pragma unroll
        for (int j = 0; j < 8; ++j)
            r[j] = fmaxf((float)sv[j] + a0[j] * inv + bb[j], 0.f);
    } else {
        float inv = 1.f / (dg + 1.f);
        half8 gv = g8[(size_t)wid * 16 + li];
        #pragma unroll
        for (int j = 0; j < 8; ++j)
            r[j] = fmaxf((a0[j] + (float)gv[j]) * inv + bb[j], 0.f);
    }
    half8 vhi, vlo;
    #pragma unroll
    for (int j = 0; j < 8; ++j) {
        h16 hi = (h16)r[j];
        vhi[j] = hi;
        vlo[j] = (h16)(r[j] - (float)hi);
    }
    *(half8*)(hhi + (size_t)wid * F + li * 8) = vhi;
    *(half8*)(hlo + (size_t)wid * F + li * 8) = vlo;
}

// ---------------- aggregation d=32, fp16 gather (64B rows, 8 rows/instr) --------
// mean, no relu: out = s[v] + agg/max(deg,1) + b   (fp32 output)
__global__ __launch_bounds__(256) void k_agg32(const h16* __restrict__ g,
        const h16* __restrict__ s, const int* __restrict__ offs,
        const int* __restrict__ csr, const float* __restrict__ degf,
        const float* __restrict__ b, float* __restrict__ out) {
    const int wid  = (int)((blockIdx.x * 256 + threadIdx.x) >> 6);
    const int lane = threadIdx.x & 63;
    if (wid >= NN) return;
    const int grp = lane >> 3;          // 8 row-groups
    const int li  = lane & 7;           // h16x4 slot within the 64B row
    const int beg = offs[wid], end = offs[wid + 1];
    const h16x4* g4 = (const h16x4*)g;  // row stride = 8 h16x4
    float a0[4] = {0.f, 0.f, 0.f, 0.f}, a1[4] = {0.f, 0.f, 0.f, 0.f};
    int e = beg + grp;
    for (; e + 8 < end; e += 16) {      // 16 rows in flight
        int u0 = csr[e], u1 = csr[e + 8];
        h16x4 v0 = g4[(size_t)u0 * 8 + li];
        h16x4 v1 = g4[(size_t)u1 * 8 + li];
        #pragma unroll
        for (int j = 0; j < 4; ++j) { a0[j] += (float)v0[j]; a1[j] += (float)v1[j]; }
    }
    if (e < end) {
        h16x4 v = g4[(size_t)csr[e] * 8 + li];
        #pragma unroll
        for (int j = 0; j < 4; ++j) a0[j] += (float)v[j];
    }
    #pragma unroll
    for (int j = 0; j < 4; ++j) {
        a0[j] += a1[j];
        a0[j] += __shfl_xor(a0[j], 8, 64);
        a0[j] += __shfl_xor(a0[j], 16, 64);
        a0[j] += __shfl_xor(a0[j], 32, 64);
    }
    if (grp) return;
    const float inv = 1.f / fmaxf(degf[wid], 1.f);
    float4 bb = ((const float4*)b)[li];
    h16x4 sv = ((const h16x4*)s)[(size_t)wid * 8 + li];
    float4 r;
    r.x = (float)sv[0] + a0[0] * inv + bb.x;
    r.y = (float)sv[1] + a0[1] * inv + bb.y;
    r.z = (float)sv[2] + a0[2] * inv + bb.z;
    r.w = (float)sv[3] + a0[3] * inv + bb.w;
    ((float4*)out)[(size_t)wid * 8 + li] = r;
}

extern "C" void kernel_launch(void* const* d_in, const int* in_sizes, int n_in,
                              void* d_out, int out_size, void* d_ws, size_t ws_size,
                              hipStream_t stream) {
    const float* x       = (const float*)d_in[0];
    const int*   src     = (const int*)  d_in[1];
    const int*   dst     = (const int*)  d_in[2];
    const float* Wself0  = (const float*)d_in[3];
    const float* Wneigh0 = (const float*)d_in[4];
    const float* b0      = (const float*)d_in[5];
    const float* Wneigh1 = (const float*)d_in[6];
    const float* b1      = (const float*)d_in[7];
    const float* Wneigh2 = (const float*)d_in[8];
    const float* b2      = (const float*)d_in[9];
    const float* Wself3  = (const float*)d_in[10];
    const float* Wneigh3 = (const float*)d_in[11];
    const float* b3      = (const float*)d_in[12];
    float* out = (float*)d_out;

    char* ws = (char*)d_ws;
    size_t off = 0;
    auto alloc = [&](size_t bytes) -> void* {
        void* p = ws + off;
        off += (bytes + 255) & ~(size_t)255;
        return p;
    };
    float* degf   = (float*)alloc((size_t)NN * 4);
    int*   offs   = (int*)  alloc((size_t)(NN + 1) * 4);
    int*   csr    = (int*)  alloc((size_t)NE * 4);
    int*   bcur   = (int*)  alloc((size_t)NBKT * 4);
    int*   barea  = (int*)  alloc((size_t)NBKT * CAP * 4);
    h16*   hhi    = (h16*)  alloc((size_t)NN * F * 2);
    h16*   hlo    = (h16*)  alloc((size_t)NN * F * 2);
    h16*   gh     = (h16*)  alloc((size_t)NN * F * 2);   // fp16 gather operand
    h16*   s16    = (h16*)  alloc((size_t)NN * F * 2);   // fp16 self operand
    h16*   WfS0   = (h16*)  alloc((size_t)128 * 128 * 2 * 2);
    h16*   WfN0   = (h16*)  alloc((size_t)128 * 128 * 2 * 2);
    h16*   WfN1   = (h16*)  alloc((size_t)128 * 128 * 2 * 2);
    h16*   WfN2   = (h16*)  alloc((size_t)128 * 128 * 2 * 2);
    h16*   WfS3   = (h16*)  alloc((size_t)128 * 32 * 2 * 2);
    h16*   WfN3   = (h16*)  alloc((size_t)128 * 32 * 2 * 2);

    const int mgrid = (NN + 63) / 64;         // 64 rows per block (4 waves x 16)

    // 1: weight prep + bucket-cursor zero
    k_pre0<<<289, 256, 0, stream>>>(Wself0, Wneigh0, Wneigh1, Wneigh2,
                                    Wself3, Wneigh3,
                                    WfS0, WfN0, WfN1, WfN2, WfS3, WfN3, bcur);
    // 2: edge partition + l2norm (independent grids, one dispatch)
    k_pre1<<<NPB + LGRID, 256, 0, stream>>>(src, dst, bcur, barea, x, hhi, hlo);
    // 3: per-bucket scan + hist + CSR fill
    k_bfill<<<NBKT, 256, 0, stream>>>(barea, bcur, offs, degf, csr);

    // layer 0 (mean): fused self+neigh GEMM (both fp16 out), then aggregate
    k_mfma<8, 8, true, true><<<mgrid, 256, 0, stream>>>(hhi, hlo, WfS0, WfN0, s16, gh);
    k_agg128<0><<<LGRID, 256, 0, stream>>>(gh, s16, offs, csr, degf, b0, hhi, hlo);

    // layer 1 (gcn)
    k_mfma<8, 0, true, false><<<mgrid, 256, 0, stream>>>(hhi, hlo, WfN1, nullptr, gh, nullptr);
    k_agg128<1><<<LGRID, 256, 0, stream>>>(gh, nullptr, offs, csr, degf, b1, hhi, hlo);

    // layer 2 (gcn)
    k_mfma<8, 0, true, false><<<mgrid, 256, 0, stream>>>(hhi, hlo, WfN2, nullptr, gh, nullptr);
    k_agg128<1><<<LGRID, 256, 0, stream>>>(gh, nullptr, offs, csr, degf, b2, hhi, hlo);

    // layer 3 (mean, 128->32): fp16 self + fp16 gather (64B rows)
    k_mfma<2, 2, true, true><<<mgrid, 256, 0, stream>>>(hhi, hlo, WfS3, WfN3, s16, gh);
    k_agg32<<<LGRID, 256, 0, stream>>>(gh, s16, offs, csr, degf, b3, out);
}